// Round 1
// baseline (1814.652 us; speedup 1.0000x reference)
//
#include <hip/hip_runtime.h>
#include <math.h>

#define NB 16
#define N0 4096
#define NE 524288

// ---------------- SAGE ----------------

static __global__ void k_sage_scatter2(const int* __restrict__ src, const int* __restrict__ dst,
                                       const float* __restrict__ x, float* __restrict__ agg,
                                       float* __restrict__ cnt) {
  int e = blockIdx.x * 256 + threadIdx.x;
  if (e >= NE) return;
  int s = src[e];
  if (s < 0) return;
  int d = dst[e];
  atomicAdd(&agg[d * 2 + 0], x[s * 2 + 0]);
  atomicAdd(&agg[d * 2 + 1], x[s * 2 + 1]);
  atomicAdd(&cnt[d], 1.0f);
}

static __global__ void k_sage_scatter64(const int* __restrict__ src, const int* __restrict__ dst,
                                        const float* __restrict__ x, float* __restrict__ agg,
                                        float* __restrict__ cnt) {
  int tid = blockIdx.x * 256 + threadIdx.x;
  int e = tid >> 4, q = tid & 15;
  if (e >= NE) return;
  int s = src[e];
  if (s < 0) return;
  int d = dst[e];
  const float4 v = *(const float4*)&x[(size_t)s * 64 + q * 4];
  float* a = &agg[(size_t)d * 64 + q * 4];
  atomicAdd(a + 0, v.x);
  atomicAdd(a + 1, v.y);
  atomicAdd(a + 2, v.z);
  atomicAdd(a + 3, v.w);
  if (q == 0) atomicAdd(&cnt[d], 1.0f);
}

template <int DIN>
static __global__ void k_sage_out(const float* __restrict__ x, const float* __restrict__ agg,
                                  const float* __restrict__ cnt,
                                  const float* __restrict__ wl, const float* __restrict__ bl,
                                  const float* __restrict__ wr, float* __restrict__ h, int ntot) {
  __shared__ float wlT[DIN][64];
  __shared__ float wrT[DIN][64];
  for (int idx = threadIdx.x; idx < DIN * 64; idx += 256) {
    int o = idx / DIN, d = idx % DIN;
    wlT[d][o] = wl[idx];
    wrT[d][o] = wr[idx];
  }
  __syncthreads();
  int o = threadIdx.x & 63, vl = threadIdx.x >> 6;
  int v = blockIdx.x * 4 + vl;
  if (v >= ntot) return;
  float inv = 1.0f / fmaxf(cnt[v], 1.0f);
  float acc = bl[o];
#pragma unroll
  for (int d = 0; d < DIN; ++d)
    acc += agg[(size_t)v * DIN + d] * inv * wlT[d][o] + x[(size_t)v * DIN + d] * wrT[d][o];
  h[(size_t)v * 64 + o] = fmaxf(acc, 0.0f);
}

// ---------------- GCN ----------------

static __global__ void k_gcn_lin(const float* __restrict__ x, const float* __restrict__ w,
                                 float* __restrict__ h1, int ntot) {
  __shared__ float wT[64][64];
  for (int idx = threadIdx.x; idx < 64 * 64; idx += 256) wT[idx & 63][idx >> 6] = w[idx];
  __syncthreads();
  int o = threadIdx.x & 63, vl = threadIdx.x >> 6;
  int v = blockIdx.x * 4 + vl;
  if (v >= ntot) return;
  float acc = 0.0f;
#pragma unroll
  for (int d = 0; d < 64; ++d) acc += x[(size_t)v * 64 + d] * wT[d][o];
  h1[(size_t)v * 64 + o] = acc;
}

static __global__ void k_gcn_deg(const int* __restrict__ src, const int* __restrict__ dst,
                                 float* __restrict__ cnt) {
  int e = blockIdx.x * 256 + threadIdx.x;
  if (e >= NE) return;
  if (src[e] < 0) return;
  atomicAdd(&cnt[dst[e]], 1.0f);
}

static __global__ void k_gcn_scatter(const int* __restrict__ src, const int* __restrict__ dst,
                                     const float* __restrict__ h1, const float* __restrict__ cnt,
                                     float* __restrict__ agg) {
  int tid = blockIdx.x * 256 + threadIdx.x;
  int e = tid >> 4, q = tid & 15;
  if (e >= NE) return;
  int s = src[e];
  if (s < 0) return;
  int d = dst[e];
  float nrm = (1.0f / sqrtf(1.0f + cnt[s])) * (1.0f / sqrtf(1.0f + cnt[d]));
  const float4 v = *(const float4*)&h1[(size_t)s * 64 + q * 4];
  float* a = &agg[(size_t)d * 64 + q * 4];
  atomicAdd(a + 0, v.x * nrm);
  atomicAdd(a + 1, v.y * nrm);
  atomicAdd(a + 2, v.z * nrm);
  atomicAdd(a + 3, v.w * nrm);
}

static __global__ void k_gcn_out(const float* __restrict__ agg, const float* __restrict__ h1,
                                 const float* __restrict__ cnt, const float* __restrict__ b,
                                 float* __restrict__ h, int ntot) {
  int t = blockIdx.x * 256 + threadIdx.x;
  if (t >= ntot * 64) return;
  int v = t >> 6, o = t & 63;
  float invdeg = 1.0f / (1.0f + cnt[v]);
  h[t] = fmaxf(agg[t] + h1[t] * invdeg + b[o], 0.0f);
}

// ---------------- TopK pool ----------------

static __global__ void k_score(const float* __restrict__ h, const float* __restrict__ p,
                               float* __restrict__ score, int ntot) {
  __shared__ float ps[64];
  __shared__ float pn;
  if (threadIdx.x < 64) ps[threadIdx.x] = p[threadIdx.x];
  __syncthreads();
  if (threadIdx.x == 0) {
    double s = 0.0;
    for (int d = 0; d < 64; ++d) s += (double)ps[d] * (double)ps[d];
    pn = (float)(1.0 / sqrt(s));
  }
  __syncthreads();
  int v = blockIdx.x * 256 + threadIdx.x;
  if (v >= ntot) return;
  double acc = 0.0;
#pragma unroll 8
  for (int d = 0; d < 64; ++d) acc += (double)h[(size_t)v * 64 + d] * (double)ps[d];
  score[v] = (float)acc * pn;
}

// exact top_k semantics: rank = #(s_j > s_i) + #(s_j == s_i && j < i); keep rank < k
static __global__ void k_rank(const float* __restrict__ score, int* __restrict__ newidx,
                              int* __restrict__ perm, int n_per, int k, int bpg) {
  __shared__ __align__(16) float sc[4096];
  int b = blockIdx.x / bpg, chunk = blockIdx.x % bpg;
  const float* s0 = score + (size_t)b * n_per;
  for (int j = threadIdx.x; j < n_per; j += 256) sc[j] = s0[j];
  __syncthreads();
  int i = chunk * 256 + threadIdx.x;
  if (i >= n_per) return;
  float si = sc[i];
  int r = 0;
  for (int j = 0; j < n_per; j += 4) {
    float4 s4 = *(const float4*)&sc[j];
    r += (s4.x > si) || (s4.x == si && (j + 0) < i);
    r += (s4.y > si) || (s4.y == si && (j + 1) < i);
    r += (s4.z > si) || (s4.z == si && (j + 2) < i);
    r += (s4.w > si) || (s4.w == si && (j + 3) < i);
  }
  int gi = b * n_per + i;
  if (r < k) {
    newidx[gi] = b * k + r;
    perm[b * k + r] = gi;
  } else {
    newidx[gi] = -1;
  }
}

static __global__ void k_gather(const float* __restrict__ h, const float* __restrict__ score,
                                const int* __restrict__ perm, float* __restrict__ xnew, int kt) {
  int t = blockIdx.x * 256 + threadIdx.x;
  if (t >= kt * 16) return;
  int nn = t >> 4, q = t & 15;
  int old = perm[nn];
  float tm = tanhf(score[old]);
  float4 v = *(const float4*)&h[(size_t)old * 64 + q * 4];
  v.x *= tm; v.y *= tm; v.z *= tm; v.w *= tm;
  *(float4*)&xnew[(size_t)nn * 64 + q * 4] = v;
}

static __global__ void k_remap(const int* __restrict__ src, const int* __restrict__ dst,
                               const int* __restrict__ newidx, int* __restrict__ nsrc,
                               int* __restrict__ ndst) {
  int e = blockIdx.x * 256 + threadIdx.x;
  if (e >= NE) return;
  int s = src[e];
  int os = -1, od = -1;
  if (s >= 0) {
    int a = newidx[s];
    int bb = newidx[dst[e]];
    if (a >= 0 && bb >= 0) { os = a; od = bb; }
  }
  nsrc[e] = os;
  ndst[e] = od;
}

static __global__ void k_readout(const float* __restrict__ xnew, float* __restrict__ z, int k) {
  int b = blockIdx.x, d = threadIdx.x;  // 64 threads = 1 wave
  const float* p = xnew + (size_t)b * k * 64 + d;
  float m = -INFINITY;
  double s = 0.0;
  for (int r = 0; r < k; ++r) {
    float v = p[(size_t)r * 64];
    m = fmaxf(m, v);
    s += v;
  }
  z[b * 128 + d] += m;
  z[b * 128 + 64 + d] += (float)(s / (double)k);
}

// ---------------- MLP + softmax ----------------

static __global__ void k_mlp(const float* __restrict__ z, const float* __restrict__ lw1,
                             const float* __restrict__ lb1, const float* __restrict__ lw2,
                             const float* __restrict__ lb2, const float* __restrict__ lw3,
                             const float* __restrict__ lb3, float* __restrict__ out) {
  __shared__ float zs[128], t1[128], t2[64], t3[256], red[256];
  int b = blockIdx.x, tid = threadIdx.x;
  if (tid < 128) zs[tid] = z[b * 128 + tid];
  __syncthreads();
  if (tid < 128) {
    double a = 0.0;
    for (int d = 0; d < 128; ++d) a += (double)lw1[tid * 128 + d] * (double)zs[d];
    t1[tid] = fmaxf((float)a + lb1[tid], 0.0f);
  }
  __syncthreads();
  if (tid < 64) {
    double a = 0.0;
    for (int d = 0; d < 128; ++d) a += (double)lw2[tid * 128 + d] * (double)t1[d];
    t2[tid] = fmaxf((float)a + lb2[tid], 0.0f);
  }
  __syncthreads();
  {
    double a = 0.0;
    for (int d = 0; d < 64; ++d) a += (double)lw3[tid * 64 + d] * (double)t2[d];
    t3[tid] = (float)a + lb3[tid];
  }
  __syncthreads();
  red[tid] = t3[tid];
  __syncthreads();
  for (int s = 128; s > 0; s >>= 1) {
    if (tid < s) red[tid] = fmaxf(red[tid], red[tid + s]);
    __syncthreads();
  }
  float mx = red[0];
  __syncthreads();
  float e = expf(t3[tid] - mx);
  red[tid] = e;
  __syncthreads();
  for (int s = 128; s > 0; s >>= 1) {
    if (tid < s) red[tid] += red[tid + s];
    __syncthreads();
  }
  out[b * 256 + tid] = e / red[0];
}

// ---------------- launch ----------------

extern "C" void kernel_launch(void* const* d_in, const int* in_sizes, int n_in,
                              void* d_out, int out_size, void* d_ws, size_t ws_size,
                              hipStream_t stream) {
  const float* x0 = (const float*)d_in[0];
  const int* esrc0 = (const int*)d_in[1];
  const int* edst0 = (const int*)d_in[2];
  const float* WL[3] = {(const float*)d_in[3], (const float*)d_in[6], (const float*)d_in[9]};
  const float* BL[3] = {(const float*)d_in[4], (const float*)d_in[7], (const float*)d_in[10]};
  const float* WR[3] = {(const float*)d_in[5], (const float*)d_in[8], (const float*)d_in[11]};
  const float* WG[3] = {(const float*)d_in[12], (const float*)d_in[14], (const float*)d_in[16]};
  const float* BG[3] = {(const float*)d_in[13], (const float*)d_in[15], (const float*)d_in[17]};
  const float* P[6] = {(const float*)d_in[18], (const float*)d_in[19], (const float*)d_in[20],
                       (const float*)d_in[21], (const float*)d_in[22], (const float*)d_in[23]};
  const float* lw1 = (const float*)d_in[24];
  const float* lb1 = (const float*)d_in[25];
  const float* lw2 = (const float*)d_in[26];
  const float* lb2 = (const float*)d_in[27];
  const float* lw3 = (const float*)d_in[28];
  const float* lb3 = (const float*)d_in[29];

  char* ws = (char*)d_ws;
  size_t off = 0;
  auto alloc = [&](size_t bytes) -> void* {
    void* p = ws + off;
    off += (bytes + 255) & ~(size_t)255;
    return p;
  };
  float* hA = (float*)alloc((size_t)65536 * 64 * 4);
  float* hB = (float*)alloc((size_t)32768 * 64 * 4);
  float* agg = (float*)alloc((size_t)32768 * 64 * 4);
  float* tmp = (float*)alloc((size_t)8192 * 64 * 4);
  float* cnt = (float*)alloc((size_t)65536 * 4);
  float* score = (float*)alloc((size_t)65536 * 4);
  int* newidx = (int*)alloc((size_t)65536 * 4);
  int* perm = (int*)alloc((size_t)32768 * 4);
  int* eAs = (int*)alloc((size_t)NE * 4);
  int* eAd = (int*)alloc((size_t)NE * 4);
  int* eBs = (int*)alloc((size_t)NE * 4);
  int* eBd = (int*)alloc((size_t)NE * 4);
  float* z = (float*)alloc((size_t)16 * 128 * 4);
  if (off > ws_size) return;  // workspace too small — bail

  hipMemsetAsync(z, 0, 16 * 128 * 4, stream);

  const float* xcur = x0;
  const int* es = esrc0;
  const int* ed = edst0;

  for (int i = 0; i < 6; ++i) {
    int n_per = N0 >> i;
    int ntot = NB * n_per;
    int k = n_per >> 1;

    if (i < 3) {
      int din = (i == 0) ? 2 : 64;
      hipMemsetAsync(agg, 0, (size_t)ntot * din * 4, stream);
      hipMemsetAsync(cnt, 0, (size_t)ntot * 4, stream);
      if (i == 0) {
        k_sage_scatter2<<<(NE + 255) / 256, 256, 0, stream>>>(es, ed, xcur, agg, cnt);
        k_sage_out<2><<<(ntot + 3) / 4, 256, 0, stream>>>(xcur, agg, cnt, WL[0], BL[0], WR[0],
                                                          hA, ntot);
      } else {
        k_sage_scatter64<<<(NE * 16 + 255) / 256, 256, 0, stream>>>(es, ed, xcur, agg, cnt);
        k_sage_out<64><<<(ntot + 3) / 4, 256, 0, stream>>>(xcur, agg, cnt, WL[i], BL[i], WR[i],
                                                           hA, ntot);
      }
    } else {
      int g = i - 3;
      k_gcn_lin<<<(ntot + 3) / 4, 256, 0, stream>>>(xcur, WG[g], tmp, ntot);
      hipMemsetAsync(agg, 0, (size_t)ntot * 64 * 4, stream);
      hipMemsetAsync(cnt, 0, (size_t)ntot * 4, stream);
      k_gcn_deg<<<(NE + 255) / 256, 256, 0, stream>>>(es, ed, cnt);
      k_gcn_scatter<<<(NE * 16 + 255) / 256, 256, 0, stream>>>(es, ed, tmp, cnt, agg);
      k_gcn_out<<<(ntot * 64 + 255) / 256, 256, 0, stream>>>(agg, tmp, cnt, BG[g], hA, ntot);
    }

    // pool i
    k_score<<<(ntot + 255) / 256, 256, 0, stream>>>(hA, P[i], score, ntot);
    int bpg = (n_per >= 256) ? (n_per / 256) : 1;
    k_rank<<<NB * bpg, 256, 0, stream>>>(score, newidx, perm, n_per, k, bpg);
    k_gather<<<(NB * k * 16 + 255) / 256, 256, 0, stream>>>(hA, score, perm, hB, NB * k);
    if (i < 5) {
      int* ns = (i & 1) ? eBs : eAs;
      int* nd = (i & 1) ? eBd : eAd;
      k_remap<<<(NE + 255) / 256, 256, 0, stream>>>(es, ed, newidx, ns, nd);
      es = ns;
      ed = nd;
    }
    k_readout<<<NB, 64, 0, stream>>>(hB, z, k);
    xcur = hB;
  }

  k_mlp<<<NB, 256, 0, stream>>>(z, lw1, lb1, lw2, lb2, lw3, lb3, (float*)d_out);
}

// Round 2
// 897.480 us; speedup vs baseline: 2.0219x; 2.0219x over previous
//
#include <hip/hip_runtime.h>
#include <math.h>

#define NB 16
#define N0 4096
#define NE 524288

// ---------------- SAGE ----------------

static __global__ void k_sage_scatter2(const int* __restrict__ src, const int* __restrict__ dst,
                                       const float* __restrict__ x, float* __restrict__ agg,
                                       float* __restrict__ cnt) {
  int e = blockIdx.x * 256 + threadIdx.x;
  if (e >= NE) return;
  int s = src[e];
  if (s < 0) return;
  int d = dst[e];
  atomicAdd(&agg[d * 2 + 0], x[s * 2 + 0]);
  atomicAdd(&agg[d * 2 + 1], x[s * 2 + 1]);
  atomicAdd(&cnt[d], 1.0f);
}

static __global__ void k_sage_scatter64(const int* __restrict__ src, const int* __restrict__ dst,
                                        const float* __restrict__ x, float* __restrict__ agg,
                                        float* __restrict__ cnt) {
  int tid = blockIdx.x * 256 + threadIdx.x;
  int e = tid >> 4, q = tid & 15;
  if (e >= NE) return;
  int s = src[e];
  if (s < 0) return;
  int d = dst[e];
  const float4 v = *(const float4*)&x[(size_t)s * 64 + q * 4];
  float* a = &agg[(size_t)d * 64 + q * 4];
  atomicAdd(a + 0, v.x);
  atomicAdd(a + 1, v.y);
  atomicAdd(a + 2, v.z);
  atomicAdd(a + 3, v.w);
  if (q == 0) atomicAdd(&cnt[d], 1.0f);
}

template <int DIN>
static __global__ void k_sage_out(const float* __restrict__ x, const float* __restrict__ agg,
                                  const float* __restrict__ cnt,
                                  const float* __restrict__ wl, const float* __restrict__ bl,
                                  const float* __restrict__ wr, float* __restrict__ h, int ntot) {
  __shared__ float wlT[DIN][64];
  __shared__ float wrT[DIN][64];
  for (int idx = threadIdx.x; idx < DIN * 64; idx += 256) {
    int o = idx / DIN, d = idx % DIN;
    wlT[d][o] = wl[idx];
    wrT[d][o] = wr[idx];
  }
  __syncthreads();
  int o = threadIdx.x & 63, vl = threadIdx.x >> 6;
  int v = blockIdx.x * 4 + vl;
  if (v >= ntot) return;
  float inv = 1.0f / fmaxf(cnt[v], 1.0f);
  float acc = bl[o];
#pragma unroll
  for (int d = 0; d < DIN; ++d)
    acc += agg[(size_t)v * DIN + d] * inv * wlT[d][o] + x[(size_t)v * DIN + d] * wrT[d][o];
  h[(size_t)v * 64 + o] = fmaxf(acc, 0.0f);
}

// ---------------- GCN ----------------

static __global__ void k_gcn_lin(const float* __restrict__ x, const float* __restrict__ w,
                                 float* __restrict__ h1, int ntot) {
  __shared__ float wT[64][64];
  for (int idx = threadIdx.x; idx < 64 * 64; idx += 256) wT[idx & 63][idx >> 6] = w[idx];
  __syncthreads();
  int o = threadIdx.x & 63, vl = threadIdx.x >> 6;
  int v = blockIdx.x * 4 + vl;
  if (v >= ntot) return;
  float acc = 0.0f;
#pragma unroll
  for (int d = 0; d < 64; ++d) acc += x[(size_t)v * 64 + d] * wT[d][o];
  h1[(size_t)v * 64 + o] = acc;
}

static __global__ void k_gcn_deg(const int* __restrict__ src, const int* __restrict__ dst,
                                 float* __restrict__ cnt) {
  int e = blockIdx.x * 256 + threadIdx.x;
  if (e >= NE) return;
  if (src[e] < 0) return;
  atomicAdd(&cnt[dst[e]], 1.0f);
}

static __global__ void k_gcn_scatter(const int* __restrict__ src, const int* __restrict__ dst,
                                     const float* __restrict__ h1, const float* __restrict__ cnt,
                                     float* __restrict__ agg) {
  int tid = blockIdx.x * 256 + threadIdx.x;
  int e = tid >> 4, q = tid & 15;
  if (e >= NE) return;
  int s = src[e];
  if (s < 0) return;
  int d = dst[e];
  float nrm = (1.0f / sqrtf(1.0f + cnt[s])) * (1.0f / sqrtf(1.0f + cnt[d]));
  const float4 v = *(const float4*)&h1[(size_t)s * 64 + q * 4];
  float* a = &agg[(size_t)d * 64 + q * 4];
  atomicAdd(a + 0, v.x * nrm);
  atomicAdd(a + 1, v.y * nrm);
  atomicAdd(a + 2, v.z * nrm);
  atomicAdd(a + 3, v.w * nrm);
}

static __global__ void k_gcn_out(const float* __restrict__ agg, const float* __restrict__ h1,
                                 const float* __restrict__ cnt, const float* __restrict__ b,
                                 float* __restrict__ h, int ntot) {
  int t = blockIdx.x * 256 + threadIdx.x;
  if (t >= ntot * 64) return;
  int v = t >> 6, o = t & 63;
  float invdeg = 1.0f / (1.0f + cnt[v]);
  h[t] = fmaxf(agg[t] + h1[t] * invdeg + b[o], 0.0f);
}

// ---------------- TopK pool ----------------

static __global__ void k_score(const float* __restrict__ h, const float* __restrict__ p,
                               float* __restrict__ score, int ntot) {
  __shared__ float ps[64];
  __shared__ float pn;
  if (threadIdx.x < 64) ps[threadIdx.x] = p[threadIdx.x];
  __syncthreads();
  if (threadIdx.x == 0) {
    double s = 0.0;
    for (int d = 0; d < 64; ++d) s += (double)ps[d] * (double)ps[d];
    pn = (float)(1.0 / sqrt(s));
  }
  __syncthreads();
  int v = blockIdx.x * 256 + threadIdx.x;
  if (v >= ntot) return;
  double acc = 0.0;
#pragma unroll 8
  for (int d = 0; d < 64; ++d) acc += (double)h[(size_t)v * 64 + d] * (double)ps[d];
  score[v] = (float)acc * pn;
}

// exact top_k semantics: rank = #(s_j > s_i) + #(s_j == s_i && j < i); keep rank < k
static __global__ void k_rank(const float* __restrict__ score, int* __restrict__ newidx,
                              int* __restrict__ perm, int n_per, int k, int bpg) {
  __shared__ __align__(16) float sc[4096];
  int b = blockIdx.x / bpg, chunk = blockIdx.x % bpg;
  const float* s0 = score + (size_t)b * n_per;
  for (int j = threadIdx.x; j < n_per; j += 256) sc[j] = s0[j];
  __syncthreads();
  int i = chunk * 256 + threadIdx.x;
  if (i >= n_per) return;
  float si = sc[i];
  int r = 0;
  for (int j = 0; j < n_per; j += 4) {
    float4 s4 = *(const float4*)&sc[j];
    r += (s4.x > si) || (s4.x == si && (j + 0) < i);
    r += (s4.y > si) || (s4.y == si && (j + 1) < i);
    r += (s4.z > si) || (s4.z == si && (j + 2) < i);
    r += (s4.w > si) || (s4.w == si && (j + 3) < i);
  }
  int gi = b * n_per + i;
  if (r < k) {
    newidx[gi] = b * k + r;
    perm[b * k + r] = gi;
  } else {
    newidx[gi] = -1;
  }
}

static __global__ void k_gather(const float* __restrict__ h, const float* __restrict__ score,
                                const int* __restrict__ perm, float* __restrict__ xnew, int kt) {
  int t = blockIdx.x * 256 + threadIdx.x;
  if (t >= kt * 16) return;
  int nn = t >> 4, q = t & 15;
  int old = perm[nn];
  float tm = tanhf(score[old]);
  float4 v = *(const float4*)&h[(size_t)old * 64 + q * 4];
  v.x *= tm; v.y *= tm; v.z *= tm; v.w *= tm;
  *(float4*)&xnew[(size_t)nn * 64 + q * 4] = v;
}

static __global__ void k_remap(const int* __restrict__ src, const int* __restrict__ dst,
                               const int* __restrict__ newidx, int* __restrict__ nsrc,
                               int* __restrict__ ndst) {
  int e = blockIdx.x * 256 + threadIdx.x;
  if (e >= NE) return;
  int s = src[e];
  int os = -1, od = -1;
  if (s >= 0) {
    int a = newidx[s];
    int bb = newidx[dst[e]];
    if (a >= 0 && bb >= 0) { os = a; od = bb; }
  }
  nsrc[e] = os;
  ndst[e] = od;
}

// ---------------- readout (two-stage parallel) ----------------

// stage 1: grid = NB * nch blocks, 256 threads. Each block reduces a 64-row
// chunk of graph b into partial max/sum[64].
static __global__ void k_readout_part(const float* __restrict__ xnew, float* __restrict__ pmax,
                                      float* __restrict__ psum, int k, int nch) {
  int b = blockIdx.x / nch, c = blockIdx.x % nch;
  int d = threadIdx.x & 63, sl = threadIdx.x >> 6;
  int rpc = k / nch;
  const float* p = xnew + ((size_t)b * k + (size_t)c * rpc) * 64 + d;
  float m = -INFINITY, s = 0.0f;
  for (int r = sl; r < rpc; r += 4) {
    float v = p[(size_t)r * 64];
    m = fmaxf(m, v);
    s += v;
  }
  __shared__ float sm[4][64], ss[4][64];
  sm[sl][d] = m;
  ss[sl][d] = s;
  __syncthreads();
  if (sl == 0) {
    m = fmaxf(fmaxf(sm[0][d], sm[1][d]), fmaxf(sm[2][d], sm[3][d]));
    s = ss[0][d] + ss[1][d] + ss[2][d] + ss[3][d];
    pmax[(size_t)blockIdx.x * 64 + d] = m;
    psum[(size_t)blockIdx.x * 64 + d] = s;
  }
}

// stage 2: grid = NB blocks, 64 threads; combine chunks, accumulate into z.
static __global__ void k_readout_comb(const float* __restrict__ pmax,
                                      const float* __restrict__ psum, float* __restrict__ z,
                                      int k, int nch) {
  int b = blockIdx.x, d = threadIdx.x;
  float m = -INFINITY, s = 0.0f;
  for (int c = 0; c < nch; ++c) {
    m = fmaxf(m, pmax[((size_t)b * nch + c) * 64 + d]);
    s += psum[((size_t)b * nch + c) * 64 + d];
  }
  z[b * 128 + d] += m;
  z[b * 128 + 64 + d] += s / (float)k;
}

// ---------------- MLP + softmax ----------------

static __global__ void k_mlp(const float* __restrict__ z, const float* __restrict__ lw1,
                             const float* __restrict__ lb1, const float* __restrict__ lw2,
                             const float* __restrict__ lb2, const float* __restrict__ lw3,
                             const float* __restrict__ lb3, float* __restrict__ out) {
  __shared__ float zs[128], t1[128], t2[64], t3[256], red[256];
  int b = blockIdx.x, tid = threadIdx.x;
  if (tid < 128) zs[tid] = z[b * 128 + tid];
  __syncthreads();
  if (tid < 128) {
    double a = 0.0;
    for (int d = 0; d < 128; ++d) a += (double)lw1[tid * 128 + d] * (double)zs[d];
    t1[tid] = fmaxf((float)a + lb1[tid], 0.0f);
  }
  __syncthreads();
  if (tid < 64) {
    double a = 0.0;
    for (int d = 0; d < 128; ++d) a += (double)lw2[tid * 128 + d] * (double)t1[d];
    t2[tid] = fmaxf((float)a + lb2[tid], 0.0f);
  }
  __syncthreads();
  {
    double a = 0.0;
    for (int d = 0; d < 64; ++d) a += (double)lw3[tid * 64 + d] * (double)t2[d];
    t3[tid] = (float)a + lb3[tid];
  }
  __syncthreads();
  red[tid] = t3[tid];
  __syncthreads();
  for (int s = 128; s > 0; s >>= 1) {
    if (tid < s) red[tid] = fmaxf(red[tid], red[tid + s]);
    __syncthreads();
  }
  float mx = red[0];
  __syncthreads();
  float e = expf(t3[tid] - mx);
  red[tid] = e;
  __syncthreads();
  for (int s = 128; s > 0; s >>= 1) {
    if (tid < s) red[tid] += red[tid + s];
    __syncthreads();
  }
  out[b * 256 + tid] = e / red[0];
}

// ---------------- launch ----------------

extern "C" void kernel_launch(void* const* d_in, const int* in_sizes, int n_in,
                              void* d_out, int out_size, void* d_ws, size_t ws_size,
                              hipStream_t stream) {
  const float* x0 = (const float*)d_in[0];
  const int* esrc0 = (const int*)d_in[1];
  const int* edst0 = (const int*)d_in[2];
  const float* WL[3] = {(const float*)d_in[3], (const float*)d_in[6], (const float*)d_in[9]};
  const float* BL[3] = {(const float*)d_in[4], (const float*)d_in[7], (const float*)d_in[10]};
  const float* WR[3] = {(const float*)d_in[5], (const float*)d_in[8], (const float*)d_in[11]};
  const float* WG[3] = {(const float*)d_in[12], (const float*)d_in[14], (const float*)d_in[16]};
  const float* BG[3] = {(const float*)d_in[13], (const float*)d_in[15], (const float*)d_in[17]};
  const float* P[6] = {(const float*)d_in[18], (const float*)d_in[19], (const float*)d_in[20],
                       (const float*)d_in[21], (const float*)d_in[22], (const float*)d_in[23]};
  const float* lw1 = (const float*)d_in[24];
  const float* lb1 = (const float*)d_in[25];
  const float* lw2 = (const float*)d_in[26];
  const float* lb2 = (const float*)d_in[27];
  const float* lw3 = (const float*)d_in[28];
  const float* lb3 = (const float*)d_in[29];

  char* ws = (char*)d_ws;
  size_t off = 0;
  auto alloc = [&](size_t bytes) -> void* {
    void* p = ws + off;
    off += (bytes + 255) & ~(size_t)255;
    return p;
  };
  float* hA = (float*)alloc((size_t)65536 * 64 * 4);
  float* hB = (float*)alloc((size_t)32768 * 64 * 4);
  float* agg = (float*)alloc((size_t)32768 * 64 * 4);
  float* tmp = (float*)alloc((size_t)8192 * 64 * 4);
  float* cnt = (float*)alloc((size_t)65536 * 4);
  float* score = (float*)alloc((size_t)65536 * 4);
  int* newidx = (int*)alloc((size_t)65536 * 4);
  int* perm = (int*)alloc((size_t)32768 * 4);
  int* eAs = (int*)alloc((size_t)NE * 4);
  int* eAd = (int*)alloc((size_t)NE * 4);
  int* eBs = (int*)alloc((size_t)NE * 4);
  int* eBd = (int*)alloc((size_t)NE * 4);
  float* z = (float*)alloc((size_t)16 * 128 * 4);
  float* pmax = (float*)alloc((size_t)NB * 32 * 64 * 4);
  float* psum = (float*)alloc((size_t)NB * 32 * 64 * 4);
  if (off > ws_size) return;  // workspace too small — bail

  hipMemsetAsync(z, 0, 16 * 128 * 4, stream);

  const float* xcur = x0;
  const int* es = esrc0;
  const int* ed = edst0;

  for (int i = 0; i < 6; ++i) {
    int n_per = N0 >> i;
    int ntot = NB * n_per;
    int k = n_per >> 1;

    if (i < 3) {
      int din = (i == 0) ? 2 : 64;
      hipMemsetAsync(agg, 0, (size_t)ntot * din * 4, stream);
      hipMemsetAsync(cnt, 0, (size_t)ntot * 4, stream);
      if (i == 0) {
        k_sage_scatter2<<<(NE + 255) / 256, 256, 0, stream>>>(es, ed, xcur, agg, cnt);
        k_sage_out<2><<<(ntot + 3) / 4, 256, 0, stream>>>(xcur, agg, cnt, WL[0], BL[0], WR[0],
                                                          hA, ntot);
      } else {
        k_sage_scatter64<<<(NE * 16 + 255) / 256, 256, 0, stream>>>(es, ed, xcur, agg, cnt);
        k_sage_out<64><<<(ntot + 3) / 4, 256, 0, stream>>>(xcur, agg, cnt, WL[i], BL[i], WR[i],
                                                           hA, ntot);
      }
    } else {
      int g = i - 3;
      k_gcn_lin<<<(ntot + 3) / 4, 256, 0, stream>>>(xcur, WG[g], tmp, ntot);
      hipMemsetAsync(agg, 0, (size_t)ntot * 64 * 4, stream);
      hipMemsetAsync(cnt, 0, (size_t)ntot * 4, stream);
      k_gcn_deg<<<(NE + 255) / 256, 256, 0, stream>>>(es, ed, cnt);
      k_gcn_scatter<<<(NE * 16 + 255) / 256, 256, 0, stream>>>(es, ed, tmp, cnt, agg);
      k_gcn_out<<<(ntot * 64 + 255) / 256, 256, 0, stream>>>(agg, tmp, cnt, BG[g], hA, ntot);
    }

    // pool i
    k_score<<<(ntot + 255) / 256, 256, 0, stream>>>(hA, P[i], score, ntot);
    int bpg = (n_per >= 256) ? (n_per / 256) : 1;
    k_rank<<<NB * bpg, 256, 0, stream>>>(score, newidx, perm, n_per, k, bpg);
    k_gather<<<(NB * k * 16 + 255) / 256, 256, 0, stream>>>(hA, score, perm, hB, NB * k);
    if (i < 5) {
      int* ns = (i & 1) ? eBs : eAs;
      int* nd = (i & 1) ? eBd : eAd;
      k_remap<<<(NE + 255) / 256, 256, 0, stream>>>(es, ed, newidx, ns, nd);
      es = ns;
      ed = nd;
    }
    // readout: two-stage parallel reduction
    int nch = (k >= 64) ? (k / 64) : 1;
    k_readout_part<<<NB * nch, 256, 0, stream>>>(hB, pmax, psum, k, nch);
    k_readout_comb<<<NB, 64, 0, stream>>>(pmax, psum, z, k, nch);
    xcur = hB;
  }

  k_mlp<<<NB, 256, 0, stream>>>(z, lw1, lb1, lw2, lb2, lw3, lb3, (float*)d_out);
}

// Round 3
// 740.330 us; speedup vs baseline: 2.4511x; 1.2123x over previous
//
#include <hip/hip_runtime.h>
#include <math.h>

#define NB 16
#define N0 4096
#define NE 524288

// ---------------- SAGE ----------------

static __global__ void k_sage_scatter2(const int* __restrict__ src, const int* __restrict__ dst,
                                       const float* __restrict__ x, float* __restrict__ agg,
                                       float* __restrict__ cnt) {
  int e = blockIdx.x * 256 + threadIdx.x;
  if (e >= NE) return;
  int s = src[e];
  if (s < 0) return;
  int d = dst[e];
  atomicAdd(&agg[d * 2 + 0], x[s * 2 + 0]);
  atomicAdd(&agg[d * 2 + 1], x[s * 2 + 1]);
  atomicAdd(&cnt[d], 1.0f);
}

static __global__ void k_sage_scatter64(const int* __restrict__ src, const int* __restrict__ dst,
                                        const float* __restrict__ x, float* __restrict__ agg,
                                        float* __restrict__ cnt) {
  int tid = blockIdx.x * 256 + threadIdx.x;
  int e = tid >> 4, q = tid & 15;
  if (e >= NE) return;
  int s = src[e];
  if (s < 0) return;
  int d = dst[e];
  const float4 v = *(const float4*)&x[(size_t)s * 64 + q * 4];
  float* a = &agg[(size_t)d * 64 + q * 4];
  atomicAdd(a + 0, v.x);
  atomicAdd(a + 1, v.y);
  atomicAdd(a + 2, v.z);
  atomicAdd(a + 3, v.w);
  if (q == 0) atomicAdd(&cnt[d], 1.0f);
}

// 16 nodes per block (4 waves x 4 nodes); padded LDS (conflict-free transpose)
template <int DIN>
static __global__ void k_sage_out(const float* __restrict__ x, const float* __restrict__ agg,
                                  const float* __restrict__ cnt,
                                  const float* __restrict__ wl, const float* __restrict__ bl,
                                  const float* __restrict__ wr, float* __restrict__ h, int ntot) {
  __shared__ float wlT[DIN][65];
  __shared__ float wrT[DIN][65];
  for (int idx = threadIdx.x; idx < DIN * 64; idx += 256) {
    int o = idx / DIN, d = idx % DIN;
    wlT[d][o] = wl[idx];
    wrT[d][o] = wr[idx];
  }
  __syncthreads();
  int o = threadIdx.x & 63, vl = threadIdx.x >> 6;
  int base = blockIdx.x * 16 + vl * 4;
#pragma unroll
  for (int r = 0; r < 4; ++r) {
    int v = base + r;
    if (v >= ntot) break;
    float inv = 1.0f / fmaxf(cnt[v], 1.0f);
    float acc = bl[o];
#pragma unroll
    for (int d = 0; d < DIN; ++d)
      acc += agg[(size_t)v * DIN + d] * inv * wlT[d][o] + x[(size_t)v * DIN + d] * wrT[d][o];
    h[(size_t)v * 64 + o] = fmaxf(acc, 0.0f);
  }
}

// ---------------- GCN ----------------

static __global__ void k_gcn_lin(const float* __restrict__ x, const float* __restrict__ w,
                                 float* __restrict__ h1, int ntot) {
  __shared__ float wT[64][65];
  for (int idx = threadIdx.x; idx < 64 * 64; idx += 256) wT[idx & 63][idx >> 6] = w[idx];
  __syncthreads();
  int o = threadIdx.x & 63, vl = threadIdx.x >> 6;
  int base = blockIdx.x * 16 + vl * 4;
#pragma unroll
  for (int r = 0; r < 4; ++r) {
    int v = base + r;
    if (v >= ntot) break;
    float acc = 0.0f;
#pragma unroll
    for (int d = 0; d < 64; ++d) acc += x[(size_t)v * 64 + d] * wT[d][o];
    h1[(size_t)v * 64 + o] = acc;
  }
}

static __global__ void k_gcn_deg(const int* __restrict__ src, const int* __restrict__ dst,
                                 float* __restrict__ cnt) {
  int e = blockIdx.x * 256 + threadIdx.x;
  if (e >= NE) return;
  if (src[e] < 0) return;
  atomicAdd(&cnt[dst[e]], 1.0f);
}

static __global__ void k_gcn_scatter(const int* __restrict__ src, const int* __restrict__ dst,
                                     const float* __restrict__ h1, const float* __restrict__ cnt,
                                     float* __restrict__ agg) {
  int tid = blockIdx.x * 256 + threadIdx.x;
  int e = tid >> 4, q = tid & 15;
  if (e >= NE) return;
  int s = src[e];
  if (s < 0) return;
  int d = dst[e];
  float nrm = (1.0f / sqrtf(1.0f + cnt[s])) * (1.0f / sqrtf(1.0f + cnt[d]));
  const float4 v = *(const float4*)&h1[(size_t)s * 64 + q * 4];
  float* a = &agg[(size_t)d * 64 + q * 4];
  atomicAdd(a + 0, v.x * nrm);
  atomicAdd(a + 1, v.y * nrm);
  atomicAdd(a + 2, v.z * nrm);
  atomicAdd(a + 3, v.w * nrm);
}

static __global__ void k_gcn_out(const float* __restrict__ agg, const float* __restrict__ h1,
                                 const float* __restrict__ cnt, const float* __restrict__ b,
                                 float* __restrict__ h, int ntot) {
  int t = blockIdx.x * 256 + threadIdx.x;
  if (t >= ntot * 64) return;
  int v = t >> 6, o = t & 63;
  float invdeg = 1.0f / (1.0f + cnt[v]);
  h[t] = fmaxf(agg[t] + h1[t] * invdeg + b[o], 0.0f);
}

// ---------------- TopK pool ----------------

static __global__ void k_score(const float* __restrict__ h, const float* __restrict__ p,
                               float* __restrict__ score, int ntot) {
  __shared__ float ps[64];
  __shared__ float pn;
  if (threadIdx.x < 64) ps[threadIdx.x] = p[threadIdx.x];
  __syncthreads();
  if (threadIdx.x == 0) {
    double s = 0.0;
    for (int d = 0; d < 64; ++d) s += (double)ps[d] * (double)ps[d];
    pn = (float)(1.0 / sqrt(s));
  }
  __syncthreads();
  int v = blockIdx.x * 256 + threadIdx.x;
  if (v >= ntot) return;
  double acc = 0.0;
#pragma unroll 8
  for (int d = 0; d < 64; ++d) acc += (double)h[(size_t)v * 64 + d] * (double)ps[d];
  score[v] = (float)acc * pn;
}

// exact top_k semantics: rank = #(s_j > s_i) + #(s_j == s_i && j < i); keep rank < k
static __global__ void k_rank(const float* __restrict__ score, int* __restrict__ newidx,
                              int* __restrict__ perm, int n_per, int k, int bpg) {
  __shared__ __align__(16) float sc[4096];
  int b = blockIdx.x / bpg, chunk = blockIdx.x % bpg;
  const float* s0 = score + (size_t)b * n_per;
  for (int j = threadIdx.x; j < n_per; j += 256) sc[j] = s0[j];
  __syncthreads();
  int i = chunk * 256 + threadIdx.x;
  if (i >= n_per) return;
  float si = sc[i];
  int r = 0;
  for (int j = 0; j < n_per; j += 4) {
    float4 s4 = *(const float4*)&sc[j];
    r += (s4.x > si) || (s4.x == si && (j + 0) < i);
    r += (s4.y > si) || (s4.y == si && (j + 1) < i);
    r += (s4.z > si) || (s4.z == si && (j + 2) < i);
    r += (s4.w > si) || (s4.w == si && (j + 3) < i);
  }
  int gi = b * n_per + i;
  if (r < k) {
    newidx[gi] = b * k + r;
    perm[b * k + r] = gi;
  } else {
    newidx[gi] = -1;
  }
}

static __global__ void k_gather(const float* __restrict__ h, const float* __restrict__ score,
                                const int* __restrict__ perm, float* __restrict__ xnew, int kt) {
  int t = blockIdx.x * 256 + threadIdx.x;
  if (t >= kt * 16) return;
  int nn = t >> 4, q = t & 15;
  int old = perm[nn];
  float tm = tanhf(score[old]);
  float4 v = *(const float4*)&h[(size_t)old * 64 + q * 4];
  v.x *= tm; v.y *= tm; v.z *= tm; v.w *= tm;
  *(float4*)&xnew[(size_t)nn * 64 + q * 4] = v;
}

static __global__ void k_remap(const int* __restrict__ src, const int* __restrict__ dst,
                               const int* __restrict__ newidx, int* __restrict__ nsrc,
                               int* __restrict__ ndst) {
  int e = blockIdx.x * 256 + threadIdx.x;
  if (e >= NE) return;
  int s = src[e];
  int os = -1, od = -1;
  if (s >= 0) {
    int a = newidx[s];
    int bb = newidx[dst[e]];
    if (a >= 0 && bb >= 0) { os = a; od = bb; }
  }
  nsrc[e] = os;
  ndst[e] = od;
}

// ---------------- readout (two-stage parallel) ----------------

static __global__ void k_readout_part(const float* __restrict__ xnew, float* __restrict__ pmax,
                                      float* __restrict__ psum, int k, int nch) {
  int b = blockIdx.x / nch, c = blockIdx.x % nch;
  int d = threadIdx.x & 63, sl = threadIdx.x >> 6;
  int rpc = k / nch;
  const float* p = xnew + ((size_t)b * k + (size_t)c * rpc) * 64 + d;
  float m = -INFINITY, s = 0.0f;
  for (int r = sl; r < rpc; r += 4) {
    float v = p[(size_t)r * 64];
    m = fmaxf(m, v);
    s += v;
  }
  __shared__ float sm[4][64], ss[4][64];
  sm[sl][d] = m;
  ss[sl][d] = s;
  __syncthreads();
  if (sl == 0) {
    m = fmaxf(fmaxf(sm[0][d], sm[1][d]), fmaxf(sm[2][d], sm[3][d]));
    s = ss[0][d] + ss[1][d] + ss[2][d] + ss[3][d];
    pmax[(size_t)blockIdx.x * 64 + d] = m;
    psum[(size_t)blockIdx.x * 64 + d] = s;
  }
}

static __global__ void k_readout_comb(const float* __restrict__ pmax,
                                      const float* __restrict__ psum, float* __restrict__ z,
                                      int k, int nch) {
  int b = blockIdx.x, d = threadIdx.x;
  float m = -INFINITY, s = 0.0f;
  for (int c = 0; c < nch; ++c) {
    m = fmaxf(m, pmax[((size_t)b * nch + c) * 64 + d]);
    s += psum[((size_t)b * nch + c) * 64 + d];
  }
  z[b * 128 + d] += m;
  z[b * 128 + 64 + d] += s / (float)k;
}

// ---------------- MLP + softmax ----------------

static __global__ void k_mlp(const float* __restrict__ z, const float* __restrict__ lw1,
                             const float* __restrict__ lb1, const float* __restrict__ lw2,
                             const float* __restrict__ lb2, const float* __restrict__ lw3,
                             const float* __restrict__ lb3, float* __restrict__ out) {
  __shared__ float zs[128], t1[128], t2[64], t3[256], red[256];
  int b = blockIdx.x, tid = threadIdx.x;
  if (tid < 128) zs[tid] = z[b * 128 + tid];
  __syncthreads();
  if (tid < 128) {
    double a = 0.0;
    for (int d = 0; d < 128; ++d) a += (double)lw1[tid * 128 + d] * (double)zs[d];
    t1[tid] = fmaxf((float)a + lb1[tid], 0.0f);
  }
  __syncthreads();
  if (tid < 64) {
    double a = 0.0;
    for (int d = 0; d < 128; ++d) a += (double)lw2[tid * 128 + d] * (double)t1[d];
    t2[tid] = fmaxf((float)a + lb2[tid], 0.0f);
  }
  __syncthreads();
  {
    double a = 0.0;
    for (int d = 0; d < 64; ++d) a += (double)lw3[tid * 64 + d] * (double)t2[d];
    t3[tid] = (float)a + lb3[tid];
  }
  __syncthreads();
  red[tid] = t3[tid];
  __syncthreads();
  for (int s = 128; s > 0; s >>= 1) {
    if (tid < s) red[tid] = fmaxf(red[tid], red[tid + s]);
    __syncthreads();
  }
  float mx = red[0];
  __syncthreads();
  float e = expf(t3[tid] - mx);
  red[tid] = e;
  __syncthreads();
  for (int s = 128; s > 0; s >>= 1) {
    if (tid < s) red[tid] += red[tid + s];
    __syncthreads();
  }
  out[b * 256 + tid] = e / red[0];
}

// ---------------- launch ----------------

extern "C" void kernel_launch(void* const* d_in, const int* in_sizes, int n_in,
                              void* d_out, int out_size, void* d_ws, size_t ws_size,
                              hipStream_t stream) {
  const float* x0 = (const float*)d_in[0];
  const int* esrc0 = (const int*)d_in[1];
  const int* edst0 = (const int*)d_in[2];
  const float* WL[3] = {(const float*)d_in[3], (const float*)d_in[6], (const float*)d_in[9]};
  const float* BL[3] = {(const float*)d_in[4], (const float*)d_in[7], (const float*)d_in[10]};
  const float* WR[3] = {(const float*)d_in[5], (const float*)d_in[8], (const float*)d_in[11]};
  const float* WG[3] = {(const float*)d_in[12], (const float*)d_in[14], (const float*)d_in[16]};
  const float* BG[3] = {(const float*)d_in[13], (const float*)d_in[15], (const float*)d_in[17]};
  const float* P[6] = {(const float*)d_in[18], (const float*)d_in[19], (const float*)d_in[20],
                       (const float*)d_in[21], (const float*)d_in[22], (const float*)d_in[23]};
  const float* lw1 = (const float*)d_in[24];
  const float* lb1 = (const float*)d_in[25];
  const float* lw2 = (const float*)d_in[26];
  const float* lb2 = (const float*)d_in[27];
  const float* lw3 = (const float*)d_in[28];
  const float* lb3 = (const float*)d_in[29];

  char* ws = (char*)d_ws;
  size_t off = 0;
  auto alloc = [&](size_t bytes) -> void* {
    void* p = ws + off;
    off += (bytes + 255) & ~(size_t)255;
    return p;
  };
  float* hA = (float*)alloc((size_t)65536 * 64 * 4);
  float* hB = (float*)alloc((size_t)32768 * 64 * 4);
  float* agg = (float*)alloc((size_t)32768 * 64 * 4);
  float* tmp = (float*)alloc((size_t)8192 * 64 * 4);
  float* cnt = (float*)alloc((size_t)65536 * 4);
  float* score = (float*)alloc((size_t)65536 * 4);
  int* newidx = (int*)alloc((size_t)65536 * 4);
  int* perm = (int*)alloc((size_t)32768 * 4);
  int* eAs = (int*)alloc((size_t)NE * 4);
  int* eAd = (int*)alloc((size_t)NE * 4);
  int* eBs = (int*)alloc((size_t)NE * 4);
  int* eBd = (int*)alloc((size_t)NE * 4);
  float* z = (float*)alloc((size_t)16 * 128 * 4);
  float* pmax = (float*)alloc((size_t)NB * 32 * 64 * 4);
  float* psum = (float*)alloc((size_t)NB * 32 * 64 * 4);
  if (off > ws_size) return;  // workspace too small — bail

  hipMemsetAsync(z, 0, 16 * 128 * 4, stream);

  const float* xcur = x0;
  const int* es = esrc0;
  const int* ed = edst0;

  for (int i = 0; i < 6; ++i) {
    int n_per = N0 >> i;
    int ntot = NB * n_per;
    int k = n_per >> 1;

    if (i < 3) {
      int din = (i == 0) ? 2 : 64;
      hipMemsetAsync(agg, 0, (size_t)ntot * din * 4, stream);
      hipMemsetAsync(cnt, 0, (size_t)ntot * 4, stream);
      if (i == 0) {
        k_sage_scatter2<<<(NE + 255) / 256, 256, 0, stream>>>(es, ed, xcur, agg, cnt);
        k_sage_out<2><<<(ntot + 15) / 16, 256, 0, stream>>>(xcur, agg, cnt, WL[0], BL[0], WR[0],
                                                            hA, ntot);
      } else {
        k_sage_scatter64<<<(NE * 16 + 255) / 256, 256, 0, stream>>>(es, ed, xcur, agg, cnt);
        k_sage_out<64><<<(ntot + 15) / 16, 256, 0, stream>>>(xcur, agg, cnt, WL[i], BL[i], WR[i],
                                                             hA, ntot);
      }
    } else {
      int g = i - 3;
      k_gcn_lin<<<(ntot + 15) / 16, 256, 0, stream>>>(xcur, WG[g], tmp, ntot);
      hipMemsetAsync(agg, 0, (size_t)ntot * 64 * 4, stream);
      hipMemsetAsync(cnt, 0, (size_t)ntot * 4, stream);
      k_gcn_deg<<<(NE + 255) / 256, 256, 0, stream>>>(es, ed, cnt);
      k_gcn_scatter<<<(NE * 16 + 255) / 256, 256, 0, stream>>>(es, ed, tmp, cnt, agg);
      k_gcn_out<<<(ntot * 64 + 255) / 256, 256, 0, stream>>>(agg, tmp, cnt, BG[g], hA, ntot);
    }

    // pool i
    k_score<<<(ntot + 255) / 256, 256, 0, stream>>>(hA, P[i], score, ntot);
    int bpg = (n_per >= 256) ? (n_per / 256) : 1;
    k_rank<<<NB * bpg, 256, 0, stream>>>(score, newidx, perm, n_per, k, bpg);
    k_gather<<<(NB * k * 16 + 255) / 256, 256, 0, stream>>>(hA, score, perm, hB, NB * k);
    if (i < 5) {
      int* ns = (i & 1) ? eBs : eAs;
      int* nd = (i & 1) ? eBd : eAd;
      k_remap<<<(NE + 255) / 256, 256, 0, stream>>>(es, ed, newidx, ns, nd);
      es = ns;
      ed = nd;
    }
    int nch = (k >= 64) ? (k / 64) : 1;
    k_readout_part<<<NB * nch, 256, 0, stream>>>(hB, pmax, psum, k, nch);
    k_readout_comb<<<NB, 64, 0, stream>>>(pmax, psum, z, k, nch);
    xcur = hB;
  }

  k_mlp<<<NB, 256, 0, stream>>>(z, lw1, lb1, lw2, lb2, lw3, lb3, (float*)d_out);
}

// Round 4
// 599.581 us; speedup vs baseline: 3.0265x; 1.2347x over previous
//
#include <hip/hip_runtime.h>
#include <math.h>

#define NB 16
#define N0 4096
#define NE 524288

// ---------------- CSR build (layer 0, atomic int cursor only) ----------------

static __global__ void k_count(const int* __restrict__ dst, int* __restrict__ cnt) {
  int e = blockIdx.x * 256 + threadIdx.x;
  if (e >= NE) return;
  atomicAdd(&cnt[dst[e]], 1);
}

static __global__ void k_fill0(const int* __restrict__ src, const int* __restrict__ dst,
                               int* __restrict__ cursor, int* __restrict__ list) {
  int e = blockIdx.x * 256 + threadIdx.x;
  if (e >= NE) return;
  int d = dst[e];
  int slot = atomicAdd(&cursor[d], 1);
  list[slot] = src[e];
}

// ---------------- exclusive scan (2-level, n <= 65536, 1024/block) ----------------

static __global__ void k_scan1(const int* __restrict__ in, int* __restrict__ out,
                               int* __restrict__ bsum, int n) {
  __shared__ int ts[256];
  int base = blockIdx.x * 1024 + threadIdx.x * 4;
  int a0 = (base + 0 < n) ? in[base + 0] : 0;
  int a1 = (base + 1 < n) ? in[base + 1] : 0;
  int a2 = (base + 2 < n) ? in[base + 2] : 0;
  int a3 = (base + 3 < n) ? in[base + 3] : 0;
  int s = a0 + a1 + a2 + a3;
  ts[threadIdx.x] = s;
  __syncthreads();
  for (int off = 1; off < 256; off <<= 1) {
    int v = (threadIdx.x >= off) ? ts[threadIdx.x - off] : 0;
    __syncthreads();
    ts[threadIdx.x] += v;
    __syncthreads();
  }
  int excl = ts[threadIdx.x] - s;
  if (base + 0 < n) out[base + 0] = excl;
  excl += a0;
  if (base + 1 < n) out[base + 1] = excl;
  excl += a1;
  if (base + 2 < n) out[base + 2] = excl;
  excl += a2;
  if (base + 3 < n) out[base + 3] = excl;
  if (threadIdx.x == 255) bsum[blockIdx.x] = ts[255];
}

static __global__ void k_scan2(int* __restrict__ bsum, int nb) {
  __shared__ int t[64];
  int i = threadIdx.x;
  int v = (i < nb) ? bsum[i] : 0;
  t[i] = v;
  __syncthreads();
  for (int off = 1; off < 64; off <<= 1) {
    int u = (i >= off) ? t[i - off] : 0;
    __syncthreads();
    t[i] += u;
    __syncthreads();
  }
  if (i < nb) bsum[i] = t[i] - v;
}

static __global__ void k_scan3(int* __restrict__ out, const int* __restrict__ bsum, int n) {
  int i = blockIdx.x * 256 + threadIdx.x;
  if (i < n) out[i] += bsum[i >> 10];
}

// ---------------- CSR compaction after pooling (no atomics) ----------------

static __global__ void k_newcount(const int* __restrict__ perm, const int* __restrict__ offs,
                                  const int* __restrict__ cnt, const int* __restrict__ list,
                                  const int* __restrict__ newidx, int* __restrict__ ncnt,
                                  int newn) {
  int nn = blockIdx.x * 256 + threadIdx.x;
  if (nn >= newn) return;
  int old = perm[nn];
  int st = offs[old], c = cnt[old];
  int cc = 0;
  for (int j = 0; j < c; ++j) cc += (newidx[list[st + j]] >= 0);
  ncnt[nn] = cc;
}

static __global__ void k_newfill(const int* __restrict__ perm, const int* __restrict__ offs,
                                 const int* __restrict__ cnt, const int* __restrict__ list,
                                 const int* __restrict__ newidx, const int* __restrict__ noffs,
                                 int* __restrict__ nlist, int newn) {
  int nn = blockIdx.x * 256 + threadIdx.x;
  if (nn >= newn) return;
  int old = perm[nn];
  int st = offs[old], c = cnt[old];
  int pos = noffs[nn];
  for (int j = 0; j < c; ++j) {
    int s2 = newidx[list[st + j]];
    if (s2 >= 0) nlist[pos++] = s2;
  }
}

// ---------------- SAGE (gather form) ----------------

static __global__ void k_sage_gather2(const float* __restrict__ x, const int* __restrict__ offs,
                                      const int* __restrict__ cnt, const int* __restrict__ list,
                                      float* __restrict__ mean, int ntot) {
  int v = blockIdx.x * 256 + threadIdx.x;
  if (v >= ntot) return;
  int st = offs[v], c = cnt[v];
  float s0 = 0.f, s1 = 0.f;
  for (int j = 0; j < c; ++j) {
    int s = list[st + j];
    s0 += x[s * 2 + 0];
    s1 += x[s * 2 + 1];
  }
  float inv = 1.0f / fmaxf((float)c, 1.0f);
  mean[v * 2 + 0] = s0 * inv;
  mean[v * 2 + 1] = s1 * inv;
}

static __global__ void k_sage_gather64(const float* __restrict__ x, const int* __restrict__ offs,
                                       const int* __restrict__ cnt, const int* __restrict__ list,
                                       float* __restrict__ mean, int ntot) {
  int lane = threadIdx.x & 63, vl = threadIdx.x >> 6;
  int v = blockIdx.x * 4 + vl;
  if (v >= ntot) return;
  int st = offs[v], c = cnt[v];
  float acc = 0.f;
  for (int j = 0; j < c; ++j) {
    int s = list[st + j];
    acc += x[(size_t)s * 64 + lane];
  }
  mean[(size_t)v * 64 + lane] = acc * (1.0f / fmaxf((float)c, 1.0f));
}

// 16 nodes per block (4 waves x 4 nodes); padded LDS (conflict-free transpose)
template <int DIN>
static __global__ void k_sage_out(const float* __restrict__ x, const float* __restrict__ mean,
                                  const float* __restrict__ wl, const float* __restrict__ bl,
                                  const float* __restrict__ wr, float* __restrict__ h, int ntot) {
  __shared__ float wlT[DIN][65];
  __shared__ float wrT[DIN][65];
  for (int idx = threadIdx.x; idx < DIN * 64; idx += 256) {
    int o = idx / DIN, d = idx % DIN;
    wlT[d][o] = wl[idx];
    wrT[d][o] = wr[idx];
  }
  __syncthreads();
  int o = threadIdx.x & 63, vl = threadIdx.x >> 6;
  int base = blockIdx.x * 16 + vl * 4;
#pragma unroll
  for (int r = 0; r < 4; ++r) {
    int v = base + r;
    if (v >= ntot) break;
    float acc = bl[o];
#pragma unroll
    for (int d = 0; d < DIN; ++d)
      acc += mean[(size_t)v * DIN + d] * wlT[d][o] + x[(size_t)v * DIN + d] * wrT[d][o];
    h[(size_t)v * 64 + o] = fmaxf(acc, 0.0f);
  }
}

// ---------------- GCN ----------------

static __global__ void k_gcn_lin(const float* __restrict__ x, const float* __restrict__ w,
                                 float* __restrict__ h1, int ntot) {
  __shared__ float wT[64][65];
  for (int idx = threadIdx.x; idx < 64 * 64; idx += 256) wT[idx & 63][idx >> 6] = w[idx];
  __syncthreads();
  int o = threadIdx.x & 63, vl = threadIdx.x >> 6;
  int base = blockIdx.x * 16 + vl * 4;
#pragma unroll
  for (int r = 0; r < 4; ++r) {
    int v = base + r;
    if (v >= ntot) break;
    float acc = 0.0f;
#pragma unroll
    for (int d = 0; d < 64; ++d) acc += x[(size_t)v * 64 + d] * wT[d][o];
    h1[(size_t)v * 64 + o] = acc;
  }
}

// fused: normalized gather + self term + bias + relu
static __global__ void k_gcn_gather(const float* __restrict__ h1, const int* __restrict__ offs,
                                    const int* __restrict__ cnt, const int* __restrict__ list,
                                    const float* __restrict__ b, float* __restrict__ h, int ntot) {
  int lane = threadIdx.x & 63, vl = threadIdx.x >> 6;
  int v = blockIdx.x * 4 + vl;
  if (v >= ntot) return;
  int st = offs[v], c = cnt[v];
  float degv = 1.0f + (float)c;
  float ivd = 1.0f / sqrtf(degv);
  float acc = 0.f;
  for (int j = 0; j < c; ++j) {
    int s = list[st + j];
    float nrm = (1.0f / sqrtf(1.0f + (float)cnt[s])) * ivd;
    acc += h1[(size_t)s * 64 + lane] * nrm;
  }
  float out = acc + h1[(size_t)v * 64 + lane] * (1.0f / degv) + b[lane];
  h[(size_t)v * 64 + lane] = fmaxf(out, 0.0f);
}

// ---------------- TopK pool ----------------

static __global__ void k_score(const float* __restrict__ h, const float* __restrict__ p,
                               float* __restrict__ score, int ntot) {
  __shared__ float ps[64];
  __shared__ float pn;
  if (threadIdx.x < 64) ps[threadIdx.x] = p[threadIdx.x];
  __syncthreads();
  if (threadIdx.x == 0) {
    double s = 0.0;
    for (int d = 0; d < 64; ++d) s += (double)ps[d] * (double)ps[d];
    pn = (float)(1.0 / sqrt(s));
  }
  __syncthreads();
  int v = blockIdx.x * 256 + threadIdx.x;
  if (v >= ntot) return;
  double acc = 0.0;
#pragma unroll 8
  for (int d = 0; d < 64; ++d) acc += (double)h[(size_t)v * 64 + d] * (double)ps[d];
  score[v] = (float)acc * pn;
}

// exact top_k semantics: rank = #(s_j > s_i) + #(s_j == s_i && j < i); keep rank < k
static __global__ void k_rank(const float* __restrict__ score, int* __restrict__ newidx,
                              int* __restrict__ perm, int n_per, int k, int bpg) {
  __shared__ __align__(16) float sc[4096];
  int b = blockIdx.x / bpg, chunk = blockIdx.x % bpg;
  const float* s0 = score + (size_t)b * n_per;
  for (int j = threadIdx.x; j < n_per; j += 256) sc[j] = s0[j];
  __syncthreads();
  int i = chunk * 256 + threadIdx.x;
  if (i >= n_per) return;
  float si = sc[i];
  int r = 0;
  for (int j = 0; j < n_per; j += 4) {
    float4 s4 = *(const float4*)&sc[j];
    r += (s4.x > si) || (s4.x == si && (j + 0) < i);
    r += (s4.y > si) || (s4.y == si && (j + 1) < i);
    r += (s4.z > si) || (s4.z == si && (j + 2) < i);
    r += (s4.w > si) || (s4.w == si && (j + 3) < i);
  }
  int gi = b * n_per + i;
  if (r < k) {
    newidx[gi] = b * k + r;
    perm[b * k + r] = gi;
  } else {
    newidx[gi] = -1;
  }
}

static __global__ void k_gather(const float* __restrict__ h, const float* __restrict__ score,
                                const int* __restrict__ perm, float* __restrict__ xnew, int kt) {
  int t = blockIdx.x * 256 + threadIdx.x;
  if (t >= kt * 16) return;
  int nn = t >> 4, q = t & 15;
  int old = perm[nn];
  float tm = tanhf(score[old]);
  float4 v = *(const float4*)&h[(size_t)old * 64 + q * 4];
  v.x *= tm; v.y *= tm; v.z *= tm; v.w *= tm;
  *(float4*)&xnew[(size_t)nn * 64 + q * 4] = v;
}

// ---------------- readout (two-stage parallel) ----------------

static __global__ void k_readout_part(const float* __restrict__ xnew, float* __restrict__ pmax,
                                      float* __restrict__ psum, int k, int nch) {
  int b = blockIdx.x / nch, c = blockIdx.x % nch;
  int d = threadIdx.x & 63, sl = threadIdx.x >> 6;
  int rpc = k / nch;
  const float* p = xnew + ((size_t)b * k + (size_t)c * rpc) * 64 + d;
  float m = -INFINITY, s = 0.0f;
  for (int r = sl; r < rpc; r += 4) {
    float v = p[(size_t)r * 64];
    m = fmaxf(m, v);
    s += v;
  }
  __shared__ float sm[4][64], ss[4][64];
  sm[sl][d] = m;
  ss[sl][d] = s;
  __syncthreads();
  if (sl == 0) {
    m = fmaxf(fmaxf(sm[0][d], sm[1][d]), fmaxf(sm[2][d], sm[3][d]));
    s = ss[0][d] + ss[1][d] + ss[2][d] + ss[3][d];
    pmax[(size_t)blockIdx.x * 64 + d] = m;
    psum[(size_t)blockIdx.x * 64 + d] = s;
  }
}

static __global__ void k_readout_comb(const float* __restrict__ pmax,
                                      const float* __restrict__ psum, float* __restrict__ z,
                                      int k, int nch) {
  int b = blockIdx.x, d = threadIdx.x;
  float m = -INFINITY, s = 0.0f;
  for (int c = 0; c < nch; ++c) {
    m = fmaxf(m, pmax[((size_t)b * nch + c) * 64 + d]);
    s += psum[((size_t)b * nch + c) * 64 + d];
  }
  z[b * 128 + d] += m;
  z[b * 128 + 64 + d] += s / (float)k;
}

// ---------------- MLP + softmax ----------------

static __global__ void k_mlp(const float* __restrict__ z, const float* __restrict__ lw1,
                             const float* __restrict__ lb1, const float* __restrict__ lw2,
                             const float* __restrict__ lb2, const float* __restrict__ lw3,
                             const float* __restrict__ lb3, float* __restrict__ out) {
  __shared__ float zs[128], t1[128], t2[64], t3[256], red[256];
  int b = blockIdx.x, tid = threadIdx.x;
  if (tid < 128) zs[tid] = z[b * 128 + tid];
  __syncthreads();
  if (tid < 128) {
    double a = 0.0;
    for (int d = 0; d < 128; ++d) a += (double)lw1[tid * 128 + d] * (double)zs[d];
    t1[tid] = fmaxf((float)a + lb1[tid], 0.0f);
  }
  __syncthreads();
  if (tid < 64) {
    double a = 0.0;
    for (int d = 0; d < 128; ++d) a += (double)lw2[tid * 128 + d] * (double)t1[d];
    t2[tid] = fmaxf((float)a + lb2[tid], 0.0f);
  }
  __syncthreads();
  {
    double a = 0.0;
    for (int d = 0; d < 64; ++d) a += (double)lw3[tid * 64 + d] * (double)t2[d];
    t3[tid] = (float)a + lb3[tid];
  }
  __syncthreads();
  red[tid] = t3[tid];
  __syncthreads();
  for (int s = 128; s > 0; s >>= 1) {
    if (tid < s) red[tid] = fmaxf(red[tid], red[tid + s]);
    __syncthreads();
  }
  float mx = red[0];
  __syncthreads();
  float e = expf(t3[tid] - mx);
  red[tid] = e;
  __syncthreads();
  for (int s = 128; s > 0; s >>= 1) {
    if (tid < s) red[tid] += red[tid + s];
    __syncthreads();
  }
  out[b * 256 + tid] = e / red[0];
}

// ---------------- launch ----------------

extern "C" void kernel_launch(void* const* d_in, const int* in_sizes, int n_in,
                              void* d_out, int out_size, void* d_ws, size_t ws_size,
                              hipStream_t stream) {
  const float* x0 = (const float*)d_in[0];
  const int* esrc0 = (const int*)d_in[1];
  const int* edst0 = (const int*)d_in[2];
  const float* WL[3] = {(const float*)d_in[3], (const float*)d_in[6], (const float*)d_in[9]};
  const float* BL[3] = {(const float*)d_in[4], (const float*)d_in[7], (const float*)d_in[10]};
  const float* WR[3] = {(const float*)d_in[5], (const float*)d_in[8], (const float*)d_in[11]};
  const float* WG[3] = {(const float*)d_in[12], (const float*)d_in[14], (const float*)d_in[16]};
  const float* BG[3] = {(const float*)d_in[13], (const float*)d_in[15], (const float*)d_in[17]};
  const float* P[6] = {(const float*)d_in[18], (const float*)d_in[19], (const float*)d_in[20],
                       (const float*)d_in[21], (const float*)d_in[22], (const float*)d_in[23]};
  const float* lw1 = (const float*)d_in[24];
  const float* lb1 = (const float*)d_in[25];
  const float* lw2 = (const float*)d_in[26];
  const float* lb2 = (const float*)d_in[27];
  const float* lw3 = (const float*)d_in[28];
  const float* lb3 = (const float*)d_in[29];

  char* ws = (char*)d_ws;
  size_t off = 0;
  auto alloc = [&](size_t bytes) -> void* {
    void* p = ws + off;
    off += (bytes + 255) & ~(size_t)255;
    return p;
  };
  float* hA = (float*)alloc((size_t)65536 * 64 * 4);
  float* hB = (float*)alloc((size_t)32768 * 64 * 4);
  float* mean = (float*)alloc((size_t)32768 * 64 * 4);
  float* tmp = (float*)alloc((size_t)8192 * 64 * 4);
  float* score = (float*)alloc((size_t)65536 * 4);
  int* newidx = (int*)alloc((size_t)65536 * 4);
  int* perm = (int*)alloc((size_t)32768 * 4);
  int* cntA = (int*)alloc((size_t)65536 * 4);
  int* cntB = (int*)alloc((size_t)65536 * 4);
  int* offsA = (int*)alloc((size_t)65536 * 4);
  int* offsB = (int*)alloc((size_t)65536 * 4);
  int* cursor = (int*)alloc((size_t)65536 * 4);
  int* bsum = (int*)alloc((size_t)64 * 4);
  int* listA = (int*)alloc((size_t)NE * 4);
  int* listB = (int*)alloc((size_t)NE * 4);
  float* z = (float*)alloc((size_t)16 * 128 * 4);
  float* pmax = (float*)alloc((size_t)NB * 32 * 64 * 4);
  float* psum = (float*)alloc((size_t)NB * 32 * 64 * 4);
  if (off > ws_size) return;  // workspace too small — bail

  auto scan = [&](int* cntp, int* offsp, int n) {
    int nblk = (n + 1023) / 1024;
    k_scan1<<<nblk, 256, 0, stream>>>(cntp, offsp, bsum, n);
    k_scan2<<<1, 64, 0, stream>>>(bsum, nblk);
    k_scan3<<<(n + 255) / 256, 256, 0, stream>>>(offsp, bsum, n);
  };

  hipMemsetAsync(z, 0, 16 * 128 * 4, stream);

  // build layer-0 CSR (dst-sorted src lists)
  hipMemsetAsync(cntA, 0, (size_t)65536 * 4, stream);
  k_count<<<NE / 256, 256, 0, stream>>>(edst0, cntA);
  scan(cntA, offsA, 65536);
  hipMemcpyAsync(cursor, offsA, (size_t)65536 * 4, hipMemcpyDeviceToDevice, stream);
  k_fill0<<<NE / 256, 256, 0, stream>>>(esrc0, edst0, cursor, listA);

  const float* xcur = x0;
  int* ccnt = cntA;
  int* coffs = offsA;
  int* clist = listA;

  for (int i = 0; i < 6; ++i) {
    int n_per = N0 >> i;
    int ntot = NB * n_per;
    int k = n_per >> 1;

    if (i == 0) {
      k_sage_gather2<<<(ntot + 255) / 256, 256, 0, stream>>>(xcur, coffs, ccnt, clist, mean, ntot);
      k_sage_out<2><<<(ntot + 15) / 16, 256, 0, stream>>>(xcur, mean, WL[0], BL[0], WR[0], hA,
                                                          ntot);
    } else if (i < 3) {
      k_sage_gather64<<<(ntot + 3) / 4, 256, 0, stream>>>(xcur, coffs, ccnt, clist, mean, ntot);
      k_sage_out<64><<<(ntot + 15) / 16, 256, 0, stream>>>(xcur, mean, WL[i], BL[i], WR[i], hA,
                                                           ntot);
    } else {
      int g = i - 3;
      k_gcn_lin<<<(ntot + 15) / 16, 256, 0, stream>>>(xcur, WG[g], tmp, ntot);
      k_gcn_gather<<<(ntot + 3) / 4, 256, 0, stream>>>(tmp, coffs, ccnt, clist, BG[g], hA, ntot);
    }

    // pool i
    k_score<<<(ntot + 255) / 256, 256, 0, stream>>>(hA, P[i], score, ntot);
    int bpg = (n_per >= 256) ? (n_per / 256) : 1;
    k_rank<<<NB * bpg, 256, 0, stream>>>(score, newidx, perm, n_per, k, bpg);
    k_gather<<<(NB * k * 16 + 255) / 256, 256, 0, stream>>>(hA, score, perm, hB, NB * k);

    if (i < 5) {
      int newn = NB * k;
      int* ncnt = (i & 1) ? cntA : cntB;
      int* noffs = (i & 1) ? offsA : offsB;
      int* nlist = (i & 1) ? listA : listB;
      k_newcount<<<(newn + 255) / 256, 256, 0, stream>>>(perm, coffs, ccnt, clist, newidx, ncnt,
                                                         newn);
      scan(ncnt, noffs, newn);
      k_newfill<<<(newn + 255) / 256, 256, 0, stream>>>(perm, coffs, ccnt, clist, newidx, noffs,
                                                        nlist, newn);
      ccnt = ncnt;
      coffs = noffs;
      clist = nlist;
    }

    int nch = (k >= 64) ? (k / 64) : 1;
    k_readout_part<<<NB * nch, 256, 0, stream>>>(hB, pmax, psum, k, nch);
    k_readout_comb<<<NB, 64, 0, stream>>>(pmax, psum, z, k, nch);
    xcur = hB;
  }

  k_mlp<<<NB, 256, 0, stream>>>(z, lw1, lb1, lw2, lb2, lw3, lb3, (float*)d_out);
}

// Round 5
// 524.823 us; speedup vs baseline: 3.4576x; 1.1424x over previous
//
#include <hip/hip_runtime.h>
#include <math.h>

#define NB 16
#define N0 4096
#define NE 524288

// ---------------- CSR build (layer 0, atomic int cursor only) ----------------

static __global__ void k_count(const int* __restrict__ dst, int* __restrict__ cnt) {
  int e = blockIdx.x * 256 + threadIdx.x;
  if (e >= NE) return;
  atomicAdd(&cnt[dst[e]], 1);
}

static __global__ void k_fill0(const int* __restrict__ src, const int* __restrict__ dst,
                               int* __restrict__ cursor, int* __restrict__ list) {
  int e = blockIdx.x * 256 + threadIdx.x;
  if (e >= NE) return;
  int d = dst[e];
  int slot = atomicAdd(&cursor[d], 1);
  list[slot] = src[e];
}

// ---------------- exclusive scan (2-level, n <= 65536, 1024/block) ----------------

static __global__ void k_scan1(const int* __restrict__ in, int* __restrict__ out,
                               int* __restrict__ bsum, int n) {
  __shared__ int ts[256];
  int base = blockIdx.x * 1024 + threadIdx.x * 4;
  int a0 = (base + 0 < n) ? in[base + 0] : 0;
  int a1 = (base + 1 < n) ? in[base + 1] : 0;
  int a2 = (base + 2 < n) ? in[base + 2] : 0;
  int a3 = (base + 3 < n) ? in[base + 3] : 0;
  int s = a0 + a1 + a2 + a3;
  ts[threadIdx.x] = s;
  __syncthreads();
  for (int off = 1; off < 256; off <<= 1) {
    int v = (threadIdx.x >= off) ? ts[threadIdx.x - off] : 0;
    __syncthreads();
    ts[threadIdx.x] += v;
    __syncthreads();
  }
  int excl = ts[threadIdx.x] - s;
  if (base + 0 < n) out[base + 0] = excl;
  excl += a0;
  if (base + 1 < n) out[base + 1] = excl;
  excl += a1;
  if (base + 2 < n) out[base + 2] = excl;
  excl += a2;
  if (base + 3 < n) out[base + 3] = excl;
  if (threadIdx.x == 255) bsum[blockIdx.x] = ts[255];
}

static __global__ void k_scan2(int* __restrict__ bsum, int nb) {
  __shared__ int t[64];
  int i = threadIdx.x;
  int v = (i < nb) ? bsum[i] : 0;
  t[i] = v;
  __syncthreads();
  for (int off = 1; off < 64; off <<= 1) {
    int u = (i >= off) ? t[i - off] : 0;
    __syncthreads();
    t[i] += u;
    __syncthreads();
  }
  if (i < nb) bsum[i] = t[i] - v;
}

static __global__ void k_scan3(int* __restrict__ out, const int* __restrict__ bsum, int n) {
  int i = blockIdx.x * 256 + threadIdx.x;
  if (i < n) out[i] += bsum[i >> 10];
}

// ---------------- CSR compaction after pooling (no atomics) ----------------

static __global__ void k_newcount(const int* __restrict__ perm, const int* __restrict__ offs,
                                  const int* __restrict__ cnt, const int* __restrict__ list,
                                  const int* __restrict__ newidx, int* __restrict__ ncnt,
                                  int newn) {
  int nn = blockIdx.x * 256 + threadIdx.x;
  if (nn >= newn) return;
  int old = perm[nn];
  int st = offs[old], c = cnt[old];
  int cc = 0;
  for (int j = 0; j < c; ++j) cc += (newidx[list[st + j]] >= 0);
  ncnt[nn] = cc;
}

static __global__ void k_newfill(const int* __restrict__ perm, const int* __restrict__ offs,
                                 const int* __restrict__ cnt, const int* __restrict__ list,
                                 const int* __restrict__ newidx, const int* __restrict__ noffs,
                                 int* __restrict__ nlist, int newn) {
  int nn = blockIdx.x * 256 + threadIdx.x;
  if (nn >= newn) return;
  int old = perm[nn];
  int st = offs[old], c = cnt[old];
  int pos = noffs[nn];
  for (int j = 0; j < c; ++j) {
    int s2 = newidx[list[st + j]];
    if (s2 >= 0) nlist[pos++] = s2;
  }
}

// ---------------- SAGE (gather form) ----------------

static __global__ void k_sage_gather2(const float* __restrict__ x, const int* __restrict__ offs,
                                      const int* __restrict__ cnt, const int* __restrict__ list,
                                      float* __restrict__ mean, int ntot) {
  int v = blockIdx.x * 256 + threadIdx.x;
  if (v >= ntot) return;
  int st = offs[v], c = cnt[v];
  float s0 = 0.f, s1 = 0.f;
  for (int j = 0; j < c; ++j) {
    int s = list[st + j];
    s0 += x[s * 2 + 0];
    s1 += x[s * 2 + 1];
  }
  float inv = 1.0f / fmaxf((float)c, 1.0f);
  mean[v * 2 + 0] = s0 * inv;
  mean[v * 2 + 1] = s1 * inv;
}

static __global__ void k_sage_gather64(const float* __restrict__ x, const int* __restrict__ offs,
                                       const int* __restrict__ cnt, const int* __restrict__ list,
                                       float* __restrict__ mean, int ntot) {
  int lane = threadIdx.x & 63, vl = threadIdx.x >> 6;
  int v = blockIdx.x * 4 + vl;
  if (v >= ntot) return;
  int st = offs[v], c = cnt[v];
  float acc = 0.f;
  for (int j = 0; j < c; ++j) {
    int s = list[st + j];
    acc += x[(size_t)s * 64 + lane];
  }
  mean[(size_t)v * 64 + lane] = acc * (1.0f / fmaxf((float)c, 1.0f));
}

// 16 nodes per block (4 waves x 4 nodes); padded LDS (conflict-free transpose)
template <int DIN>
static __global__ void k_sage_out(const float* __restrict__ x, const float* __restrict__ mean,
                                  const float* __restrict__ wl, const float* __restrict__ bl,
                                  const float* __restrict__ wr, float* __restrict__ h, int ntot) {
  __shared__ float wlT[DIN][65];
  __shared__ float wrT[DIN][65];
  for (int idx = threadIdx.x; idx < DIN * 64; idx += 256) {
    int o = idx / DIN, d = idx % DIN;
    wlT[d][o] = wl[idx];
    wrT[d][o] = wr[idx];
  }
  __syncthreads();
  int o = threadIdx.x & 63, vl = threadIdx.x >> 6;
  int base = blockIdx.x * 16 + vl * 4;
#pragma unroll
  for (int r = 0; r < 4; ++r) {
    int v = base + r;
    if (v >= ntot) break;
    float acc = bl[o];
#pragma unroll
    for (int d = 0; d < DIN; ++d)
      acc += mean[(size_t)v * DIN + d] * wlT[d][o] + x[(size_t)v * DIN + d] * wrT[d][o];
    h[(size_t)v * 64 + o] = fmaxf(acc, 0.0f);
  }
}

// ---------------- GCN ----------------

static __global__ void k_gcn_lin(const float* __restrict__ x, const float* __restrict__ w,
                                 float* __restrict__ h1, int ntot) {
  __shared__ float wT[64][65];
  for (int idx = threadIdx.x; idx < 64 * 64; idx += 256) wT[idx & 63][idx >> 6] = w[idx];
  __syncthreads();
  int o = threadIdx.x & 63, vl = threadIdx.x >> 6;
  int base = blockIdx.x * 16 + vl * 4;
#pragma unroll
  for (int r = 0; r < 4; ++r) {
    int v = base + r;
    if (v >= ntot) break;
    float acc = 0.0f;
#pragma unroll
    for (int d = 0; d < 64; ++d) acc += x[(size_t)v * 64 + d] * wT[d][o];
    h1[(size_t)v * 64 + o] = acc;
  }
}

// fused: normalized gather + self term + bias + relu
static __global__ void k_gcn_gather(const float* __restrict__ h1, const int* __restrict__ offs,
                                    const int* __restrict__ cnt, const int* __restrict__ list,
                                    const float* __restrict__ b, float* __restrict__ h, int ntot) {
  int lane = threadIdx.x & 63, vl = threadIdx.x >> 6;
  int v = blockIdx.x * 4 + vl;
  if (v >= ntot) return;
  int st = offs[v], c = cnt[v];
  float degv = 1.0f + (float)c;
  float ivd = 1.0f / sqrtf(degv);
  float acc = 0.f;
  for (int j = 0; j < c; ++j) {
    int s = list[st + j];
    float nrm = (1.0f / sqrtf(1.0f + (float)cnt[s])) * ivd;
    acc += h1[(size_t)s * 64 + lane] * nrm;
  }
  float out = acc + h1[(size_t)v * 64 + lane] * (1.0f / degv) + b[lane];
  h[(size_t)v * 64 + lane] = fmaxf(out, 0.0f);
}

// ---------------- TopK pool ----------------

static __global__ void k_score(const float* __restrict__ h, const float* __restrict__ p,
                               float* __restrict__ score, int ntot) {
  __shared__ float ps[64];
  __shared__ float pn;
  if (threadIdx.x < 64) ps[threadIdx.x] = p[threadIdx.x];
  __syncthreads();
  if (threadIdx.x == 0) {
    double s = 0.0;
    for (int d = 0; d < 64; ++d) s += (double)ps[d] * (double)ps[d];
    pn = (float)(1.0 / sqrt(s));
  }
  __syncthreads();
  int v = blockIdx.x * 256 + threadIdx.x;
  if (v >= ntot) return;
  double acc = 0.0;
#pragma unroll 8
  for (int d = 0; d < 64; ++d) acc += (double)h[(size_t)v * 64 + d] * (double)ps[d];
  score[v] = (float)acc * pn;
}

// bitonic sort per graph on packed keys: ascending uint64 == (score desc, idx asc)
// == exact jax.lax.top_k order (stable ties). position r -> perm/newidx directly.
static __global__ void k_sortrank(const float* __restrict__ score, int* __restrict__ newidx,
                                  int* __restrict__ perm, int n_per, int k) {
  extern __shared__ unsigned long long keys[];
  int b = blockIdx.x;
  const float* s0 = score + (size_t)b * n_per;
  int nt = blockDim.x;
  for (int i = threadIdx.x; i < n_per; i += nt) {
    unsigned u = __float_as_uint(s0[i]);
    unsigned s = (u & 0x80000000u) ? u : ~(u | 0x80000000u);  // asc key = desc float
    keys[i] = ((unsigned long long)s << 32) | (unsigned)i;
  }
  __syncthreads();
  for (int ksz = 2; ksz <= n_per; ksz <<= 1) {
    for (int j = ksz >> 1; j > 0; j >>= 1) {
      for (int i = threadIdx.x; i < n_per; i += nt) {
        int ixj = i ^ j;
        if (ixj > i) {
          unsigned long long a = keys[i], c = keys[ixj];
          bool up = ((i & ksz) == 0);
          if ((a > c) == up) {
            keys[i] = c;
            keys[ixj] = a;
          }
        }
      }
      __syncthreads();
    }
  }
  for (int r = threadIdx.x; r < n_per; r += nt) {
    int idx = (int)(keys[r] & 0xFFFFFFFFu);
    int gi = b * n_per + idx;
    if (r < k) {
      perm[b * k + r] = gi;
      newidx[gi] = b * k + r;
    } else {
      newidx[gi] = -1;
    }
  }
}

static __global__ void k_gather(const float* __restrict__ h, const float* __restrict__ score,
                                const int* __restrict__ perm, float* __restrict__ xnew, int kt) {
  int t = blockIdx.x * 256 + threadIdx.x;
  if (t >= kt * 16) return;
  int nn = t >> 4, q = t & 15;
  int old = perm[nn];
  float tm = tanhf(score[old]);
  float4 v = *(const float4*)&h[(size_t)old * 64 + q * 4];
  v.x *= tm; v.y *= tm; v.z *= tm; v.w *= tm;
  *(float4*)&xnew[(size_t)nn * 64 + q * 4] = v;
}

// ---------------- readout (two-stage parallel) ----------------

static __global__ void k_readout_part(const float* __restrict__ xnew, float* __restrict__ pmax,
                                      float* __restrict__ psum, int k, int nch) {
  int b = blockIdx.x / nch, c = blockIdx.x % nch;
  int d = threadIdx.x & 63, sl = threadIdx.x >> 6;
  int rpc = k / nch;
  const float* p = xnew + ((size_t)b * k + (size_t)c * rpc) * 64 + d;
  float m = -INFINITY, s = 0.0f;
  for (int r = sl; r < rpc; r += 4) {
    float v = p[(size_t)r * 64];
    m = fmaxf(m, v);
    s += v;
  }
  __shared__ float sm[4][64], ss[4][64];
  sm[sl][d] = m;
  ss[sl][d] = s;
  __syncthreads();
  if (sl == 0) {
    m = fmaxf(fmaxf(sm[0][d], sm[1][d]), fmaxf(sm[2][d], sm[3][d]));
    s = ss[0][d] + ss[1][d] + ss[2][d] + ss[3][d];
    pmax[(size_t)blockIdx.x * 64 + d] = m;
    psum[(size_t)blockIdx.x * 64 + d] = s;
  }
}

static __global__ void k_readout_comb(const float* __restrict__ pmax,
                                      const float* __restrict__ psum, float* __restrict__ z,
                                      int k, int nch) {
  int b = blockIdx.x, d = threadIdx.x;
  float m = -INFINITY, s = 0.0f;
  for (int c = 0; c < nch; ++c) {
    m = fmaxf(m, pmax[((size_t)b * nch + c) * 64 + d]);
    s += psum[((size_t)b * nch + c) * 64 + d];
  }
  z[b * 128 + d] += m;
  z[b * 128 + 64 + d] += s / (float)k;
}

// ---------------- MLP + softmax ----------------

static __global__ void k_mlp(const float* __restrict__ z, const float* __restrict__ lw1,
                             const float* __restrict__ lb1, const float* __restrict__ lw2,
                             const float* __restrict__ lb2, const float* __restrict__ lw3,
                             const float* __restrict__ lb3, float* __restrict__ out) {
  __shared__ float zs[128], t1[128], t2[64], t3[256], red[256];
  int b = blockIdx.x, tid = threadIdx.x;
  if (tid < 128) zs[tid] = z[b * 128 + tid];
  __syncthreads();
  if (tid < 128) {
    double a = 0.0;
    for (int d = 0; d < 128; ++d) a += (double)lw1[tid * 128 + d] * (double)zs[d];
    t1[tid] = fmaxf((float)a + lb1[tid], 0.0f);
  }
  __syncthreads();
  if (tid < 64) {
    double a = 0.0;
    for (int d = 0; d < 128; ++d) a += (double)lw2[tid * 128 + d] * (double)t1[d];
    t2[tid] = fmaxf((float)a + lb2[tid], 0.0f);
  }
  __syncthreads();
  {
    double a = 0.0;
    for (int d = 0; d < 64; ++d) a += (double)lw3[tid * 64 + d] * (double)t2[d];
    t3[tid] = (float)a + lb3[tid];
  }
  __syncthreads();
  red[tid] = t3[tid];
  __syncthreads();
  for (int s = 128; s > 0; s >>= 1) {
    if (tid < s) red[tid] = fmaxf(red[tid], red[tid + s]);
    __syncthreads();
  }
  float mx = red[0];
  __syncthreads();
  float e = expf(t3[tid] - mx);
  red[tid] = e;
  __syncthreads();
  for (int s = 128; s > 0; s >>= 1) {
    if (tid < s) red[tid] += red[tid + s];
    __syncthreads();
  }
  out[b * 256 + tid] = e / red[0];
}

// ---------------- launch ----------------

extern "C" void kernel_launch(void* const* d_in, const int* in_sizes, int n_in,
                              void* d_out, int out_size, void* d_ws, size_t ws_size,
                              hipStream_t stream) {
  const float* x0 = (const float*)d_in[0];
  const int* esrc0 = (const int*)d_in[1];
  const int* edst0 = (const int*)d_in[2];
  const float* WL[3] = {(const float*)d_in[3], (const float*)d_in[6], (const float*)d_in[9]};
  const float* BL[3] = {(const float*)d_in[4], (const float*)d_in[7], (const float*)d_in[10]};
  const float* WR[3] = {(const float*)d_in[5], (const float*)d_in[8], (const float*)d_in[11]};
  const float* WG[3] = {(const float*)d_in[12], (const float*)d_in[14], (const float*)d_in[16]};
  const float* BG[3] = {(const float*)d_in[13], (const float*)d_in[15], (const float*)d_in[17]};
  const float* P[6] = {(const float*)d_in[18], (const float*)d_in[19], (const float*)d_in[20],
                       (const float*)d_in[21], (const float*)d_in[22], (const float*)d_in[23]};
  const float* lw1 = (const float*)d_in[24];
  const float* lb1 = (const float*)d_in[25];
  const float* lw2 = (const float*)d_in[26];
  const float* lb2 = (const float*)d_in[27];
  const float* lw3 = (const float*)d_in[28];
  const float* lb3 = (const float*)d_in[29];

  char* ws = (char*)d_ws;
  size_t off = 0;
  auto alloc = [&](size_t bytes) -> void* {
    void* p = ws + off;
    off += (bytes + 255) & ~(size_t)255;
    return p;
  };
  float* hA = (float*)alloc((size_t)65536 * 64 * 4);
  float* hB = (float*)alloc((size_t)32768 * 64 * 4);
  float* mean = (float*)alloc((size_t)32768 * 64 * 4);
  float* tmp = (float*)alloc((size_t)8192 * 64 * 4);
  float* score = (float*)alloc((size_t)65536 * 4);
  int* newidx = (int*)alloc((size_t)65536 * 4);
  int* perm = (int*)alloc((size_t)32768 * 4);
  int* cntA = (int*)alloc((size_t)65536 * 4);
  int* cntB = (int*)alloc((size_t)65536 * 4);
  int* offsA = (int*)alloc((size_t)65536 * 4);
  int* offsB = (int*)alloc((size_t)65536 * 4);
  int* cursor = (int*)alloc((size_t)65536 * 4);
  int* bsum = (int*)alloc((size_t)64 * 4);
  int* listA = (int*)alloc((size_t)NE * 4);
  int* listB = (int*)alloc((size_t)NE * 4);
  float* z = (float*)alloc((size_t)16 * 128 * 4);
  float* pmax = (float*)alloc((size_t)NB * 32 * 64 * 4);
  float* psum = (float*)alloc((size_t)NB * 32 * 64 * 4);
  if (off > ws_size) return;  // workspace too small — bail

  auto scan = [&](int* cntp, int* offsp, int n) {
    int nblk = (n + 1023) / 1024;
    k_scan1<<<nblk, 256, 0, stream>>>(cntp, offsp, bsum, n);
    k_scan2<<<1, 64, 0, stream>>>(bsum, nblk);
    k_scan3<<<(n + 255) / 256, 256, 0, stream>>>(offsp, bsum, n);
  };

  hipMemsetAsync(z, 0, 16 * 128 * 4, stream);

  // build layer-0 CSR (dst-sorted src lists)
  hipMemsetAsync(cntA, 0, (size_t)65536 * 4, stream);
  k_count<<<NE / 256, 256, 0, stream>>>(edst0, cntA);
  scan(cntA, offsA, 65536);
  hipMemcpyAsync(cursor, offsA, (size_t)65536 * 4, hipMemcpyDeviceToDevice, stream);
  k_fill0<<<NE / 256, 256, 0, stream>>>(esrc0, edst0, cursor, listA);

  const float* xcur = x0;
  int* ccnt = cntA;
  int* coffs = offsA;
  int* clist = listA;

  for (int i = 0; i < 6; ++i) {
    int n_per = N0 >> i;
    int ntot = NB * n_per;
    int k = n_per >> 1;

    if (i == 0) {
      k_sage_gather2<<<(ntot + 255) / 256, 256, 0, stream>>>(xcur, coffs, ccnt, clist, mean, ntot);
      k_sage_out<2><<<(ntot + 15) / 16, 256, 0, stream>>>(xcur, mean, WL[0], BL[0], WR[0], hA,
                                                          ntot);
    } else if (i < 3) {
      k_sage_gather64<<<(ntot + 3) / 4, 256, 0, stream>>>(xcur, coffs, ccnt, clist, mean, ntot);
      k_sage_out<64><<<(ntot + 15) / 16, 256, 0, stream>>>(xcur, mean, WL[i], BL[i], WR[i], hA,
                                                           ntot);
    } else {
      int g = i - 3;
      k_gcn_lin<<<(ntot + 15) / 16, 256, 0, stream>>>(xcur, WG[g], tmp, ntot);
      k_gcn_gather<<<(ntot + 3) / 4, 256, 0, stream>>>(tmp, coffs, ccnt, clist, BG[g], hA, ntot);
    }

    // pool i
    k_score<<<(ntot + 255) / 256, 256, 0, stream>>>(hA, P[i], score, ntot);
    k_sortrank<<<NB, 1024, (size_t)n_per * 8, stream>>>(score, newidx, perm, n_per, k);
    k_gather<<<(NB * k * 16 + 255) / 256, 256, 0, stream>>>(hA, score, perm, hB, NB * k);

    if (i < 5) {
      int newn = NB * k;
      int* ncnt = (i & 1) ? cntA : cntB;
      int* noffs = (i & 1) ? offsA : offsB;
      int* nlist = (i & 1) ? listA : listB;
      k_newcount<<<(newn + 255) / 256, 256, 0, stream>>>(perm, coffs, ccnt, clist, newidx, ncnt,
                                                         newn);
      scan(ncnt, noffs, newn);
      k_newfill<<<(newn + 255) / 256, 256, 0, stream>>>(perm, coffs, ccnt, clist, newidx, noffs,
                                                        nlist, newn);
      ccnt = ncnt;
      coffs = noffs;
      clist = nlist;
    }

    int nch = (k >= 64) ? (k / 64) : 1;
    k_readout_part<<<NB * nch, 256, 0, stream>>>(hB, pmax, psum, k, nch);
    k_readout_comb<<<NB, 64, 0, stream>>>(pmax, psum, z, k, nch);
    xcur = hB;
  }

  k_mlp<<<NB, 256, 0, stream>>>(z, lw1, lb1, lw2, lb2, lw3, lb3, (float*)d_out);
}

// Round 6
// 472.637 us; speedup vs baseline: 3.8394x; 1.1104x over previous
//
#include <hip/hip_runtime.h>
#include <math.h>

#define NB 16
#define N0 4096
#define NE 524288

// ---------------- CSR build (layer 0, atomic int cursor only) ----------------

static __global__ void k_count(const int* __restrict__ dst, int* __restrict__ cnt) {
  int e = blockIdx.x * 256 + threadIdx.x;
  if (e >= NE) return;
  atomicAdd(&cnt[dst[e]], 1);
}

static __global__ void k_fill0(const int* __restrict__ src, const int* __restrict__ dst,
                               int* __restrict__ cursor, int* __restrict__ list) {
  int e = blockIdx.x * 256 + threadIdx.x;
  if (e >= NE) return;
  int d = dst[e];
  int slot = atomicAdd(&cursor[d], 1);
  list[slot] = src[e];
}

// ---------------- exclusive scan (2-level, n <= 65536, 1024/block) ----------------

static __global__ void k_scan1(const int* __restrict__ in, int* __restrict__ out,
                               int* __restrict__ bsum, int n) {
  __shared__ int ts[256];
  int base = blockIdx.x * 1024 + threadIdx.x * 4;
  int a0 = (base + 0 < n) ? in[base + 0] : 0;
  int a1 = (base + 1 < n) ? in[base + 1] : 0;
  int a2 = (base + 2 < n) ? in[base + 2] : 0;
  int a3 = (base + 3 < n) ? in[base + 3] : 0;
  int s = a0 + a1 + a2 + a3;
  ts[threadIdx.x] = s;
  __syncthreads();
  for (int off = 1; off < 256; off <<= 1) {
    int v = (threadIdx.x >= off) ? ts[threadIdx.x - off] : 0;
    __syncthreads();
    ts[threadIdx.x] += v;
    __syncthreads();
  }
  int excl = ts[threadIdx.x] - s;
  if (base + 0 < n) out[base + 0] = excl;
  excl += a0;
  if (base + 1 < n) out[base + 1] = excl;
  excl += a1;
  if (base + 2 < n) out[base + 2] = excl;
  excl += a2;
  if (base + 3 < n) out[base + 3] = excl;
  if (threadIdx.x == 255) bsum[blockIdx.x] = ts[255];
}

static __global__ void k_scan2(int* __restrict__ bsum, int nb) {
  __shared__ int t[64];
  int i = threadIdx.x;
  int v = (i < nb) ? bsum[i] : 0;
  t[i] = v;
  __syncthreads();
  for (int off = 1; off < 64; off <<= 1) {
    int u = (i >= off) ? t[i - off] : 0;
    __syncthreads();
    t[i] += u;
    __syncthreads();
  }
  if (i < nb) bsum[i] = t[i] - v;
}

static __global__ void k_scan3(int* __restrict__ out, const int* __restrict__ bsum, int n) {
  int i = blockIdx.x * 256 + threadIdx.x;
  if (i < n) out[i] += bsum[i >> 10];
}

// ---------------- CSR compaction after pooling (no atomics) ----------------

static __global__ void k_newcount(const int* __restrict__ perm, const int* __restrict__ offs,
                                  const int* __restrict__ cnt, const int* __restrict__ list,
                                  const int* __restrict__ newidx, int* __restrict__ ncnt,
                                  int newn) {
  int nn = blockIdx.x * 256 + threadIdx.x;
  if (nn >= newn) return;
  int old = perm[nn];
  int st = offs[old], c = cnt[old];
  int cc = 0;
  for (int j = 0; j < c; ++j) cc += (newidx[list[st + j]] >= 0);
  ncnt[nn] = cc;
}

static __global__ void k_newfill(const int* __restrict__ perm, const int* __restrict__ offs,
                                 const int* __restrict__ cnt, const int* __restrict__ list,
                                 const int* __restrict__ newidx, const int* __restrict__ noffs,
                                 int* __restrict__ nlist, int newn) {
  int nn = blockIdx.x * 256 + threadIdx.x;
  if (nn >= newn) return;
  int old = perm[nn];
  int st = offs[old], c = cnt[old];
  int pos = noffs[nn];
  for (int j = 0; j < c; ++j) {
    int s2 = newidx[list[st + j]];
    if (s2 >= 0) nlist[pos++] = s2;
  }
}

// ---------------- SAGE (gather form) ----------------

static __global__ void k_sage_gather2(const float* __restrict__ x, const int* __restrict__ offs,
                                      const int* __restrict__ cnt, const int* __restrict__ list,
                                      float* __restrict__ mean, int ntot) {
  int v = blockIdx.x * 256 + threadIdx.x;
  if (v >= ntot) return;
  int st = offs[v], c = cnt[v];
  float s0 = 0.f, s1 = 0.f;
  for (int j = 0; j < c; ++j) {
    int s = list[st + j];
    s0 += x[s * 2 + 0];
    s1 += x[s * 2 + 1];
  }
  float inv = 1.0f / fmaxf((float)c, 1.0f);
  mean[v * 2 + 0] = s0 * inv;
  mean[v * 2 + 1] = s1 * inv;
}

static __global__ void k_sage_gather64(const float* __restrict__ x, const int* __restrict__ offs,
                                       const int* __restrict__ cnt, const int* __restrict__ list,
                                       float* __restrict__ mean, int ntot) {
  int lane = threadIdx.x & 63, vl = threadIdx.x >> 6;
  int v = blockIdx.x * 4 + vl;
  if (v >= ntot) return;
  int st = offs[v], c = cnt[v];
  float acc = 0.f;
  for (int j = 0; j < c; ++j) {
    int s = list[st + j];
    acc += x[(size_t)s * 64 + lane];
  }
  mean[(size_t)v * 64 + lane] = acc * (1.0f / fmaxf((float)c, 1.0f));
}

// 16 nodes per block (4 waves x 4 nodes); padded LDS (conflict-free transpose)
template <int DIN>
static __global__ void k_sage_out(const float* __restrict__ x, const float* __restrict__ mean,
                                  const float* __restrict__ wl, const float* __restrict__ bl,
                                  const float* __restrict__ wr, float* __restrict__ h, int ntot) {
  __shared__ float wlT[DIN][65];
  __shared__ float wrT[DIN][65];
  for (int idx = threadIdx.x; idx < DIN * 64; idx += 256) {
    int o = idx / DIN, d = idx % DIN;
    wlT[d][o] = wl[idx];
    wrT[d][o] = wr[idx];
  }
  __syncthreads();
  int o = threadIdx.x & 63, vl = threadIdx.x >> 6;
  int base = blockIdx.x * 16 + vl * 4;
#pragma unroll
  for (int r = 0; r < 4; ++r) {
    int v = base + r;
    if (v >= ntot) break;
    float acc = bl[o];
#pragma unroll
    for (int d = 0; d < DIN; ++d)
      acc += mean[(size_t)v * DIN + d] * wlT[d][o] + x[(size_t)v * DIN + d] * wrT[d][o];
    h[(size_t)v * 64 + o] = fmaxf(acc, 0.0f);
  }
}

// ---------------- GCN ----------------

static __global__ void k_gcn_lin(const float* __restrict__ x, const float* __restrict__ w,
                                 float* __restrict__ h1, int ntot) {
  __shared__ float wT[64][65];
  for (int idx = threadIdx.x; idx < 64 * 64; idx += 256) wT[idx & 63][idx >> 6] = w[idx];
  __syncthreads();
  int o = threadIdx.x & 63, vl = threadIdx.x >> 6;
  int base = blockIdx.x * 16 + vl * 4;
#pragma unroll
  for (int r = 0; r < 4; ++r) {
    int v = base + r;
    if (v >= ntot) break;
    float acc = 0.0f;
#pragma unroll
    for (int d = 0; d < 64; ++d) acc += x[(size_t)v * 64 + d] * wT[d][o];
    h1[(size_t)v * 64 + o] = acc;
  }
}

// fused: normalized gather + self term + bias + relu
static __global__ void k_gcn_gather(const float* __restrict__ h1, const int* __restrict__ offs,
                                    const int* __restrict__ cnt, const int* __restrict__ list,
                                    const float* __restrict__ b, float* __restrict__ h, int ntot) {
  int lane = threadIdx.x & 63, vl = threadIdx.x >> 6;
  int v = blockIdx.x * 4 + vl;
  if (v >= ntot) return;
  int st = offs[v], c = cnt[v];
  float degv = 1.0f + (float)c;
  float ivd = 1.0f / sqrtf(degv);
  float acc = 0.f;
  for (int j = 0; j < c; ++j) {
    int s = list[st + j];
    float nrm = (1.0f / sqrtf(1.0f + (float)cnt[s])) * ivd;
    acc += h1[(size_t)s * 64 + lane] * nrm;
  }
  float out = acc + h1[(size_t)v * 64 + lane] * (1.0f / degv) + b[lane];
  h[(size_t)v * 64 + lane] = fmaxf(out, 0.0f);
}

// ---------------- TopK pool ----------------

static __global__ void k_score(const float* __restrict__ h, const float* __restrict__ p,
                               float* __restrict__ score, int ntot) {
  __shared__ float ps[64];
  __shared__ float pn;
  if (threadIdx.x < 64) ps[threadIdx.x] = p[threadIdx.x];
  __syncthreads();
  if (threadIdx.x == 0) {
    double s = 0.0;
    for (int d = 0; d < 64; ++d) s += (double)ps[d] * (double)ps[d];
    pn = (float)(1.0 / sqrt(s));
  }
  __syncthreads();
  int v = blockIdx.x * 256 + threadIdx.x;
  if (v >= ntot) return;
  double acc = 0.0;
#pragma unroll 8
  for (int d = 0; d < 64; ++d) acc += (double)h[(size_t)v * 64 + d] * (double)ps[d];
  score[v] = (float)acc * pn;
}

// Multi-block sort: 256-elem chunks bitonic-sorted in LDS, then log2 merge-path
// rounds. Keys: asc uint64 = (score desc, idx asc) == exact jax.lax.top_k order.

static __global__ void k_chunksort(const float* __restrict__ score,
                                   unsigned long long* __restrict__ runs, int n_per, int k,
                                   int* __restrict__ newidx, int* __restrict__ perm, int single) {
  extern __shared__ unsigned long long sk[];
  int CH = blockDim.x;
  int g0 = blockIdx.x * CH;
  int b = g0 / n_per;
  int i = threadIdx.x;
  int gi = g0 + i;
  int li = gi - b * n_per;
  unsigned u = __float_as_uint(score[gi]);
  unsigned s = (u & 0x80000000u) ? u : ~(u | 0x80000000u);
  sk[i] = ((unsigned long long)s << 32) | (unsigned)li;
  __syncthreads();
  for (int ksz = 2; ksz <= CH; ksz <<= 1) {
    for (int j = ksz >> 1; j > 0; j >>= 1) {
      int ixj = i ^ j;
      if (ixj > i) {
        unsigned long long a = sk[i], c = sk[ixj];
        bool up = ((i & ksz) == 0);
        if ((a > c) == up) {
          sk[i] = c;
          sk[ixj] = a;
        }
      }
      __syncthreads();
    }
  }
  if (!single) {
    runs[gi] = sk[i];
  } else {
    int r = i;
    int idx = (int)(sk[r] & 0xFFFFFFFFu);
    int gidx = b * n_per + idx;
    if (r < k) {
      perm[b * k + r] = gidx;
      newidx[gidx] = b * k + r;
    } else {
      newidx[gidx] = -1;
    }
  }
}

// merge pairs of sorted runs of length L; each element binary-searches its
// sibling run for its final position (keys distinct -> bijective scatter).
static __global__ void k_merge(const unsigned long long* __restrict__ in,
                               unsigned long long* __restrict__ out, int L, int ntot, int n_per,
                               int k, int* __restrict__ newidx, int* __restrict__ perm,
                               int final) {
  int g = blockIdx.x * 256 + threadIdx.x;
  if (g >= ntot) return;
  unsigned long long key = in[g];
  int pair = g / (2 * L);
  int base = pair * 2 * L;
  int t = g - base;
  const unsigned long long* sib;
  int p;
  if (t < L) {
    sib = in + base + L;
    p = t;
  } else {
    sib = in + base;
    p = t - L;
  }
  int lo = 0, hi = L;
  while (lo < hi) {
    int mid = (lo + hi) >> 1;
    lo = (sib[mid] < key) ? mid + 1 : lo;
    hi = (sib[mid] < key) ? hi : mid;
  }
  int pos = p + lo;
  if (!final) {
    out[base + pos] = key;
  } else {
    // 2L == n_per: base = b*n_per, pos = rank within graph
    int b = base / n_per;
    int idx = (int)(key & 0xFFFFFFFFu);
    int gidx = b * n_per + idx;
    if (pos < k) {
      perm[b * k + pos] = gidx;
      newidx[gidx] = b * k + pos;
    } else {
      newidx[gidx] = -1;
    }
  }
}

static __global__ void k_gather(const float* __restrict__ h, const float* __restrict__ score,
                                const int* __restrict__ perm, float* __restrict__ xnew, int kt) {
  int t = blockIdx.x * 256 + threadIdx.x;
  if (t >= kt * 16) return;
  int nn = t >> 4, q = t & 15;
  int old = perm[nn];
  float tm = tanhf(score[old]);
  float4 v = *(const float4*)&h[(size_t)old * 64 + q * 4];
  v.x *= tm; v.y *= tm; v.z *= tm; v.w *= tm;
  *(float4*)&xnew[(size_t)nn * 64 + q * 4] = v;
}

// ---------------- readout (two-stage parallel) ----------------

static __global__ void k_readout_part(const float* __restrict__ xnew, float* __restrict__ pmax,
                                      float* __restrict__ psum, int k, int nch) {
  int b = blockIdx.x / nch, c = blockIdx.x % nch;
  int d = threadIdx.x & 63, sl = threadIdx.x >> 6;
  int rpc = k / nch;
  const float* p = xnew + ((size_t)b * k + (size_t)c * rpc) * 64 + d;
  float m = -INFINITY, s = 0.0f;
  for (int r = sl; r < rpc; r += 4) {
    float v = p[(size_t)r * 64];
    m = fmaxf(m, v);
    s += v;
  }
  __shared__ float sm[4][64], ss[4][64];
  sm[sl][d] = m;
  ss[sl][d] = s;
  __syncthreads();
  if (sl == 0) {
    m = fmaxf(fmaxf(sm[0][d], sm[1][d]), fmaxf(sm[2][d], sm[3][d]));
    s = ss[0][d] + ss[1][d] + ss[2][d] + ss[3][d];
    pmax[(size_t)blockIdx.x * 64 + d] = m;
    psum[(size_t)blockIdx.x * 64 + d] = s;
  }
}

static __global__ void k_readout_comb(const float* __restrict__ pmax,
                                      const float* __restrict__ psum, float* __restrict__ z,
                                      int k, int nch) {
  int b = blockIdx.x, d = threadIdx.x;
  float m = -INFINITY, s = 0.0f;
  for (int c = 0; c < nch; ++c) {
    m = fmaxf(m, pmax[((size_t)b * nch + c) * 64 + d]);
    s += psum[((size_t)b * nch + c) * 64 + d];
  }
  z[b * 128 + d] += m;
  z[b * 128 + 64 + d] += s / (float)k;
}

// ---------------- MLP + softmax ----------------

static __global__ void k_mlp(const float* __restrict__ z, const float* __restrict__ lw1,
                             const float* __restrict__ lb1, const float* __restrict__ lw2,
                             const float* __restrict__ lb2, const float* __restrict__ lw3,
                             const float* __restrict__ lb3, float* __restrict__ out) {
  __shared__ float zs[128], t1[128], t2[64], t3[256], red[256];
  int b = blockIdx.x, tid = threadIdx.x;
  if (tid < 128) zs[tid] = z[b * 128 + tid];
  __syncthreads();
  if (tid < 128) {
    double a = 0.0;
    for (int d = 0; d < 128; ++d) a += (double)lw1[tid * 128 + d] * (double)zs[d];
    t1[tid] = fmaxf((float)a + lb1[tid], 0.0f);
  }
  __syncthreads();
  if (tid < 64) {
    double a = 0.0;
    for (int d = 0; d < 128; ++d) a += (double)lw2[tid * 128 + d] * (double)t1[d];
    t2[tid] = fmaxf((float)a + lb2[tid], 0.0f);
  }
  __syncthreads();
  {
    double a = 0.0;
    for (int d = 0; d < 64; ++d) a += (double)lw3[tid * 64 + d] * (double)t2[d];
    t3[tid] = (float)a + lb3[tid];
  }
  __syncthreads();
  red[tid] = t3[tid];
  __syncthreads();
  for (int s = 128; s > 0; s >>= 1) {
    if (tid < s) red[tid] = fmaxf(red[tid], red[tid + s]);
    __syncthreads();
  }
  float mx = red[0];
  __syncthreads();
  float e = expf(t3[tid] - mx);
  red[tid] = e;
  __syncthreads();
  for (int s = 128; s > 0; s >>= 1) {
    if (tid < s) red[tid] += red[tid + s];
    __syncthreads();
  }
  out[b * 256 + tid] = e / red[0];
}

// ---------------- launch ----------------

extern "C" void kernel_launch(void* const* d_in, const int* in_sizes, int n_in,
                              void* d_out, int out_size, void* d_ws, size_t ws_size,
                              hipStream_t stream) {
  const float* x0 = (const float*)d_in[0];
  const int* esrc0 = (const int*)d_in[1];
  const int* edst0 = (const int*)d_in[2];
  const float* WL[3] = {(const float*)d_in[3], (const float*)d_in[6], (const float*)d_in[9]};
  const float* BL[3] = {(const float*)d_in[4], (const float*)d_in[7], (const float*)d_in[10]};
  const float* WR[3] = {(const float*)d_in[5], (const float*)d_in[8], (const float*)d_in[11]};
  const float* WG[3] = {(const float*)d_in[12], (const float*)d_in[14], (const float*)d_in[16]};
  const float* BG[3] = {(const float*)d_in[13], (const float*)d_in[15], (const float*)d_in[17]};
  const float* P[6] = {(const float*)d_in[18], (const float*)d_in[19], (const float*)d_in[20],
                       (const float*)d_in[21], (const float*)d_in[22], (const float*)d_in[23]};
  const float* lw1 = (const float*)d_in[24];
  const float* lb1 = (const float*)d_in[25];
  const float* lw2 = (const float*)d_in[26];
  const float* lb2 = (const float*)d_in[27];
  const float* lw3 = (const float*)d_in[28];
  const float* lb3 = (const float*)d_in[29];

  char* ws = (char*)d_ws;
  size_t off = 0;
  auto alloc = [&](size_t bytes) -> void* {
    void* p = ws + off;
    off += (bytes + 255) & ~(size_t)255;
    return p;
  };
  float* hA = (float*)alloc((size_t)65536 * 64 * 4);
  float* hB = (float*)alloc((size_t)32768 * 64 * 4);
  float* mean = (float*)alloc((size_t)32768 * 64 * 4);
  float* tmp = (float*)alloc((size_t)8192 * 64 * 4);
  float* score = (float*)alloc((size_t)65536 * 4);
  int* newidx = (int*)alloc((size_t)65536 * 4);
  int* perm = (int*)alloc((size_t)32768 * 4);
  int* cntA = (int*)alloc((size_t)65536 * 4);
  int* cntB = (int*)alloc((size_t)65536 * 4);
  int* offsA = (int*)alloc((size_t)65536 * 4);
  int* offsB = (int*)alloc((size_t)65536 * 4);
  int* cursor = (int*)alloc((size_t)65536 * 4);
  int* bsum = (int*)alloc((size_t)64 * 4);
  int* listA = (int*)alloc((size_t)NE * 4);
  int* listB = (int*)alloc((size_t)NE * 4);
  float* z = (float*)alloc((size_t)16 * 128 * 4);
  float* pmax = (float*)alloc((size_t)NB * 32 * 64 * 4);
  float* psum = (float*)alloc((size_t)NB * 32 * 64 * 4);
  unsigned long long* keyA = (unsigned long long*)alloc((size_t)65536 * 8);
  unsigned long long* keyB = (unsigned long long*)alloc((size_t)65536 * 8);
  if (off > ws_size) return;  // workspace too small — bail

  auto scan = [&](int* cntp, int* offsp, int n) {
    int nblk = (n + 1023) / 1024;
    k_scan1<<<nblk, 256, 0, stream>>>(cntp, offsp, bsum, n);
    k_scan2<<<1, 64, 0, stream>>>(bsum, nblk);
    k_scan3<<<(n + 255) / 256, 256, 0, stream>>>(offsp, bsum, n);
  };

  hipMemsetAsync(z, 0, 16 * 128 * 4, stream);

  // build layer-0 CSR (dst-sorted src lists)
  hipMemsetAsync(cntA, 0, (size_t)65536 * 4, stream);
  k_count<<<NE / 256, 256, 0, stream>>>(edst0, cntA);
  scan(cntA, offsA, 65536);
  hipMemcpyAsync(cursor, offsA, (size_t)65536 * 4, hipMemcpyDeviceToDevice, stream);
  k_fill0<<<NE / 256, 256, 0, stream>>>(esrc0, edst0, cursor, listA);

  const float* xcur = x0;
  int* ccnt = cntA;
  int* coffs = offsA;
  int* clist = listA;

  for (int i = 0; i < 6; ++i) {
    int n_per = N0 >> i;
    int ntot = NB * n_per;
    int k = n_per >> 1;

    if (i == 0) {
      k_sage_gather2<<<(ntot + 255) / 256, 256, 0, stream>>>(xcur, coffs, ccnt, clist, mean, ntot);
      k_sage_out<2><<<(ntot + 15) / 16, 256, 0, stream>>>(xcur, mean, WL[0], BL[0], WR[0], hA,
                                                          ntot);
    } else if (i < 3) {
      k_sage_gather64<<<(ntot + 3) / 4, 256, 0, stream>>>(xcur, coffs, ccnt, clist, mean, ntot);
      k_sage_out<64><<<(ntot + 15) / 16, 256, 0, stream>>>(xcur, mean, WL[i], BL[i], WR[i], hA,
                                                           ntot);
    } else {
      int g = i - 3;
      k_gcn_lin<<<(ntot + 15) / 16, 256, 0, stream>>>(xcur, WG[g], tmp, ntot);
      k_gcn_gather<<<(ntot + 3) / 4, 256, 0, stream>>>(tmp, coffs, ccnt, clist, BG[g], hA, ntot);
    }

    // pool i: chunk sort + merge-path rounds
    k_score<<<(ntot + 255) / 256, 256, 0, stream>>>(hA, P[i], score, ntot);
    int CH = (n_per < 256) ? n_per : 256;
    int single = (CH == n_per) ? 1 : 0;
    k_chunksort<<<ntot / CH, CH, (size_t)CH * 8, stream>>>(score, keyA, n_per, k, newidx, perm,
                                                           single);
    if (!single) {
      unsigned long long* cur = keyA;
      unsigned long long* nxt = keyB;
      for (int L = CH; L * 2 <= n_per; L <<= 1) {
        int fin = (L * 2 == n_per) ? 1 : 0;
        k_merge<<<(ntot + 255) / 256, 256, 0, stream>>>(cur, nxt, L, ntot, n_per, k, newidx, perm,
                                                        fin);
        unsigned long long* t = cur;
        cur = nxt;
        nxt = t;
      }
    }
    k_gather<<<(NB * k * 16 + 255) / 256, 256, 0, stream>>>(hA, score, perm, hB, NB * k);

    if (i < 5) {
      int newn = NB * k;
      int* ncnt = (i & 1) ? cntA : cntB;
      int* noffs = (i & 1) ? offsA : offsB;
      int* nlist = (i & 1) ? listA : listB;
      k_newcount<<<(newn + 255) / 256, 256, 0, stream>>>(perm, coffs, ccnt, clist, newidx, ncnt,
                                                         newn);
      scan(ncnt, noffs, newn);
      k_newfill<<<(newn + 255) / 256, 256, 0, stream>>>(perm, coffs, ccnt, clist, newidx, noffs,
                                                        nlist, newn);
      ccnt = ncnt;
      coffs = noffs;
      clist = nlist;
    }

    int nch = (k >= 64) ? (k / 64) : 1;
    k_readout_part<<<NB * nch, 256, 0, stream>>>(hB, pmax, psum, k, nch);
    k_readout_comb<<<NB, 64, 0, stream>>>(pmax, psum, z, k, nch);
    xcur = hB;
  }

  k_mlp<<<NB, 256, 0, stream>>>(z, lw1, lb1, lw2, lb2, lw3, lb3, (float*)d_out);
}

// Round 7
// 418.833 us; speedup vs baseline: 4.3326x; 1.1285x over previous
//
#include <hip/hip_runtime.h>
#include <math.h>

#define NB 16
#define N0 4096
#define NE 524288

// ---------------- CSR build (layer 0, atomic int cursor only) ----------------

static __global__ void k_count(const int* __restrict__ dst, int* __restrict__ cnt) {
  int e = blockIdx.x * 256 + threadIdx.x;
  if (e >= NE) return;
  atomicAdd(&cnt[dst[e]], 1);
}

static __global__ void k_fill0(const int* __restrict__ src, const int* __restrict__ dst,
                               int* __restrict__ cursor, int* __restrict__ list) {
  int e = blockIdx.x * 256 + threadIdx.x;
  if (e >= NE) return;
  int d = dst[e];
  int slot = atomicAdd(&cursor[d], 1);
  list[slot] = src[e];
}

// ---------------- exclusive scan (2-level, n <= 65536, 1024/block) ----------------

static __global__ void k_scan1(const int* __restrict__ in, int* __restrict__ out,
                               int* __restrict__ bsum, int n) {
  __shared__ int ts[256];
  int base = blockIdx.x * 1024 + threadIdx.x * 4;
  int a0 = (base + 0 < n) ? in[base + 0] : 0;
  int a1 = (base + 1 < n) ? in[base + 1] : 0;
  int a2 = (base + 2 < n) ? in[base + 2] : 0;
  int a3 = (base + 3 < n) ? in[base + 3] : 0;
  int s = a0 + a1 + a2 + a3;
  ts[threadIdx.x] = s;
  __syncthreads();
  for (int off = 1; off < 256; off <<= 1) {
    int v = (threadIdx.x >= off) ? ts[threadIdx.x - off] : 0;
    __syncthreads();
    ts[threadIdx.x] += v;
    __syncthreads();
  }
  int excl = ts[threadIdx.x] - s;
  if (base + 0 < n) out[base + 0] = excl;
  excl += a0;
  if (base + 1 < n) out[base + 1] = excl;
  excl += a1;
  if (base + 2 < n) out[base + 2] = excl;
  excl += a2;
  if (base + 3 < n) out[base + 3] = excl;
  if (threadIdx.x == 255) bsum[blockIdx.x] = ts[255];
}

static __global__ void k_scan2(int* __restrict__ bsum, int nb) {
  __shared__ int t[64];
  int i = threadIdx.x;
  int v = (i < nb) ? bsum[i] : 0;
  t[i] = v;
  __syncthreads();
  for (int off = 1; off < 64; off <<= 1) {
    int u = (i >= off) ? t[i - off] : 0;
    __syncthreads();
    t[i] += u;
    __syncthreads();
  }
  if (i < nb) bsum[i] = t[i] - v;
}

static __global__ void k_scan3(int* __restrict__ out, const int* __restrict__ bsum, int n) {
  int i = blockIdx.x * 256 + threadIdx.x;
  if (i < n) out[i] += bsum[i >> 10];
}

// ---------------- CSR compaction after pooling (no atomics) ----------------

static __global__ void k_newcount(const int* __restrict__ perm, const int* __restrict__ offs,
                                  const int* __restrict__ cnt, const int* __restrict__ list,
                                  const int* __restrict__ newidx, int* __restrict__ ncnt,
                                  int newn) {
  int nn = blockIdx.x * 256 + threadIdx.x;
  if (nn >= newn) return;
  int old = perm[nn];
  int st = offs[old], c = cnt[old];
  int cc = 0;
  for (int j = 0; j < c; ++j) cc += (newidx[list[st + j]] >= 0);
  ncnt[nn] = cc;
}

static __global__ void k_newfill(const int* __restrict__ perm, const int* __restrict__ offs,
                                 const int* __restrict__ cnt, const int* __restrict__ list,
                                 const int* __restrict__ newidx, const int* __restrict__ noffs,
                                 int* __restrict__ nlist, int newn) {
  int nn = blockIdx.x * 256 + threadIdx.x;
  if (nn >= newn) return;
  int old = perm[nn];
  int st = offs[old], c = cnt[old];
  int pos = noffs[nn];
  for (int j = 0; j < c; ++j) {
    int s2 = newidx[list[st + j]];
    if (s2 >= 0) nlist[pos++] = s2;
  }
}

// ---------------- p-norms (all 6 layers, once) ----------------

static __global__ void k_pnorm(const float* __restrict__ p0, const float* __restrict__ p1,
                               const float* __restrict__ p2, const float* __restrict__ p3,
                               const float* __restrict__ p4, const float* __restrict__ p5,
                               float* __restrict__ pnbuf) {
  const float* pp = p0;
  switch (blockIdx.x) {
    case 1: pp = p1; break;
    case 2: pp = p2; break;
    case 3: pp = p3; break;
    case 4: pp = p4; break;
    case 5: pp = p5; break;
    default: break;
  }
  double v = (double)pp[threadIdx.x];
  v *= v;
#pragma unroll
  for (int off = 1; off < 64; off <<= 1) v += __shfl_xor(v, off);
  if (threadIdx.x == 0) pnbuf[blockIdx.x] = (float)(1.0 / sqrt(v));
}

// ---------------- SAGE (gather form) ----------------

static __global__ void k_sage_gather2(const float* __restrict__ x, const int* __restrict__ offs,
                                      const int* __restrict__ cnt, const int* __restrict__ list,
                                      float* __restrict__ mean, int ntot) {
  int v = blockIdx.x * 256 + threadIdx.x;
  if (v >= ntot) return;
  int st = offs[v], c = cnt[v];
  float s0 = 0.f, s1 = 0.f;
  for (int j = 0; j < c; ++j) {
    int s = list[st + j];
    s0 += x[s * 2 + 0];
    s1 += x[s * 2 + 1];
  }
  float inv = 1.0f / fmaxf((float)c, 1.0f);
  mean[v * 2 + 0] = s0 * inv;
  mean[v * 2 + 1] = s1 * inv;
}

static __global__ void k_sage_gather64(const float* __restrict__ x, const int* __restrict__ offs,
                                       const int* __restrict__ cnt, const int* __restrict__ list,
                                       float* __restrict__ mean, int ntot) {
  int lane = threadIdx.x & 63, vl = threadIdx.x >> 6;
  int v = blockIdx.x * 4 + vl;
  if (v >= ntot) return;
  int st = offs[v], c = cnt[v];
  float acc = 0.f;
  for (int j = 0; j < c; ++j) {
    int s = list[st + j];
    acc += x[(size_t)s * 64 + lane];
  }
  mean[(size_t)v * 64 + lane] = acc * (1.0f / fmaxf((float)c, 1.0f));
}

// layer-0 SAGE (DIN=2) + fused score (wave butterfly, double)
static __global__ void k_sage0(const float* __restrict__ x, const float* __restrict__ mean,
                               const float* __restrict__ wl, const float* __restrict__ blv,
                               const float* __restrict__ wr, const float* __restrict__ pvec,
                               const float* __restrict__ pnbuf, float* __restrict__ h,
                               float* __restrict__ score, int ntot) {
  __shared__ float wlT[2][65], wrT[2][65];
  if (threadIdx.x < 128) {
    int o = threadIdx.x >> 1, d = threadIdx.x & 1;
    wlT[d][o] = wl[o * 2 + d];
    wrT[d][o] = wr[o * 2 + d];
  }
  __syncthreads();
  int o = threadIdx.x & 63, vl = threadIdx.x >> 6;
  int base = blockIdx.x * 16 + vl * 4;
  float pn = pnbuf[0];
  float psl = pvec[o];
#pragma unroll
  for (int r = 0; r < 4; ++r) {
    int v = base + r;
    if (v >= ntot) break;
    float acc = blv[o] + mean[v * 2 + 0] * wlT[0][o] + mean[v * 2 + 1] * wlT[1][o] +
                x[v * 2 + 0] * wrT[0][o] + x[v * 2 + 1] * wrT[1][o];
    float hval = fmaxf(acc, 0.0f);
    h[(size_t)v * 64 + o] = hval;
    double sc = (double)hval * (double)psl;
#pragma unroll
    for (int off = 1; off < 64; off <<= 1) sc += __shfl_xor(sc, off);
    if (o == 0) score[v] = (float)sc * pn;
  }
}

// tiled GEMM SAGE for DIN=64: 64-node tile, 4x4 register tile/thread,
// A-tiles transposed + XOR-swizzled in LDS (aligned b128, conflict-free reads).
// Fused bias+relu+score epilogue.
static __global__ __launch_bounds__(256) void k_sage_mm(
    const float* __restrict__ x, const float* __restrict__ mean, const float* __restrict__ wl,
    const float* __restrict__ blv, const float* __restrict__ wr, const float* __restrict__ pvec,
    const float* __restrict__ pnbuf, int pidx, float* __restrict__ h,
    float* __restrict__ score) {
  __shared__ float smem[16384];
  __shared__ float psh[64], bsh[64];
  float* xT = smem;
  float* mT = smem + 4096;
  float* wlT = smem + 8192;
  float* wrT = smem + 12288;
  int t = threadIdx.x;
  size_t nb = blockIdx.x;

  const float4* wl4 = (const float4*)wl;
  const float4* wr4 = (const float4*)wr;
  for (int i4 = t; i4 < 1024; i4 += 256) {
    int o = i4 >> 4, db = (i4 & 15) << 2;
    float4 L = wl4[i4], R = wr4[i4];
    float Lv[4] = {L.x, L.y, L.z, L.w}, Rv[4] = {R.x, R.y, R.z, R.w};
    int og = o >> 2, o3 = o & 3;
#pragma unroll
    for (int j = 0; j < 4; ++j) {
      int d = db + j;
      int col = ((og ^ (d & 15)) << 2) | o3;
      wlT[(d << 6) + col] = Lv[j];
      wrT[(d << 6) + col] = Rv[j];
    }
  }
  if (t < 64) {
    psh[t] = pvec[t];
    bsh[t] = blv[t];
  }
  const float4* x4 = (const float4*)(x + nb * 4096);
  const float4* m4 = (const float4*)(mean + nb * 4096);
  for (int i = t; i < 1024; i += 256) {
    int node = i >> 4, db = (i & 15) << 2;
    float4 a = x4[i], m = m4[i];
    float av[4] = {a.x, a.y, a.z, a.w}, mv[4] = {m.x, m.y, m.z, m.w};
    int ng = node >> 2, n0 = node & 3;
#pragma unroll
    for (int j = 0; j < 4; ++j) {
      int d = db + j;
      int col = ((ng ^ (d & 15)) << 2) | n0;
      xT[(d << 6) + col] = av[j];
      mT[(d << 6) + col] = mv[j];
    }
  }
  __syncthreads();

  int tx = t & 15, ty = t >> 4;
  float acc[4][4] = {};
#pragma unroll 4
  for (int k = 0; k < 64; ++k) {
    int s = k & 15;
    int ca = (tx ^ s) << 2, cb = (ty ^ s) << 2;
    const float4 a = *(const float4*)&xT[(k << 6) + ca];
    const float4 m = *(const float4*)&mT[(k << 6) + ca];
    const float4 L = *(const float4*)&wlT[(k << 6) + cb];
    const float4 R = *(const float4*)&wrT[(k << 6) + cb];
    float A[4] = {a.x, a.y, a.z, a.w}, M[4] = {m.x, m.y, m.z, m.w};
    float Lv[4] = {L.x, L.y, L.z, L.w}, Rv[4] = {R.x, R.y, R.z, R.w};
#pragma unroll
    for (int r = 0; r < 4; ++r)
#pragma unroll
      for (int c = 0; c < 4; ++c) acc[r][c] += M[r] * Lv[c] + A[r] * Rv[c];
  }

  float pn = pnbuf[pidx];
  float hv[4][4];
  double sp[4];
#pragma unroll
  for (int r = 0; r < 4; ++r) {
    sp[r] = 0.0;
#pragma unroll
    for (int c = 0; c < 4; ++c) {
      float v = fmaxf(acc[r][c] + bsh[(ty << 2) + c], 0.0f);
      hv[r][c] = v;
      sp[r] += (double)v * (double)psh[(ty << 2) + c];
    }
  }
  __syncthreads();  // reuse smem
  float* hT = smem;                       // stride 68, swizzled col
  double* sred = (double*)(smem + 8192);  // [16][64]
#pragma unroll
  for (int r = 0; r < 4; ++r) {
    int node = (tx << 2) + r;
    int nk = node & 15;
#pragma unroll
    for (int c = 0; c < 4; ++c) hT[node * 68 + (((ty ^ nk) << 2) | c)] = hv[r][c];
    sred[(ty << 6) + node] = sp[r];
  }
  __syncthreads();
  float4* h4 = (float4*)(h + nb * 4096);
  for (int i = t; i < 1024; i += 256) {
    int node = i >> 4, q = i & 15;
    h4[i] = *(const float4*)&hT[node * 68 + ((q ^ (node & 15)) << 2)];
  }
  if (t < 64) {
    double ssum = 0.0;
    for (int g = 0; g < 16; ++g) ssum += sred[(g << 6) + t];
    score[nb * 64 + t] = (float)ssum * pn;
  }
}

// tiled GEMM h1 = x @ W^T (GCN linear)
static __global__ __launch_bounds__(256) void k_gcn_mm(const float* __restrict__ x,
                                                       const float* __restrict__ w,
                                                       float* __restrict__ h1) {
  __shared__ float smem[8192];
  float* xT = smem;
  float* wT = smem + 4096;
  int t = threadIdx.x;
  size_t nb = blockIdx.x;
  const float4* w4 = (const float4*)w;
  for (int i4 = t; i4 < 1024; i4 += 256) {
    int o = i4 >> 4, db = (i4 & 15) << 2;
    float4 W = w4[i4];
    float Wv[4] = {W.x, W.y, W.z, W.w};
    int og = o >> 2, o3 = o & 3;
#pragma unroll
    for (int j = 0; j < 4; ++j) {
      int d = db + j;
      wT[(d << 6) + (((og ^ (d & 15)) << 2) | o3)] = Wv[j];
    }
  }
  const float4* x4 = (const float4*)(x + nb * 4096);
  for (int i = t; i < 1024; i += 256) {
    int node = i >> 4, db = (i & 15) << 2;
    float4 a = x4[i];
    float av[4] = {a.x, a.y, a.z, a.w};
    int ng = node >> 2, n0 = node & 3;
#pragma unroll
    for (int j = 0; j < 4; ++j) {
      int d = db + j;
      xT[(d << 6) + (((ng ^ (d & 15)) << 2) | n0)] = av[j];
    }
  }
  __syncthreads();
  int tx = t & 15, ty = t >> 4;
  float acc[4][4] = {};
#pragma unroll 4
  for (int k = 0; k < 64; ++k) {
    int s = k & 15;
    const float4 a = *(const float4*)&xT[(k << 6) + ((tx ^ s) << 2)];
    const float4 W = *(const float4*)&wT[(k << 6) + ((ty ^ s) << 2)];
    float A[4] = {a.x, a.y, a.z, a.w}, Wv[4] = {W.x, W.y, W.z, W.w};
#pragma unroll
    for (int r = 0; r < 4; ++r)
#pragma unroll
      for (int c = 0; c < 4; ++c) acc[r][c] += A[r] * Wv[c];
  }
  __syncthreads();
  float* hT = smem;  // stride 68
#pragma unroll
  for (int r = 0; r < 4; ++r) {
    int node = (tx << 2) + r;
    int nk = node & 15;
#pragma unroll
    for (int c = 0; c < 4; ++c) hT[node * 68 + (((ty ^ nk) << 2) | c)] = acc[r][c];
  }
  __syncthreads();
  float4* h4 = (float4*)(h1 + nb * 4096);
  for (int i = t; i < 1024; i += 256) {
    int node = i >> 4, q = i & 15;
    h4[i] = *(const float4*)&hT[node * 68 + ((q ^ (node & 15)) << 2)];
  }
}

// fused: normalized gather + self term + bias + relu + score
static __global__ void k_gcn_gather(const float* __restrict__ h1, const int* __restrict__ offs,
                                    const int* __restrict__ cnt, const int* __restrict__ list,
                                    const float* __restrict__ b, const float* __restrict__ pvec,
                                    const float* __restrict__ pnbuf, int pidx,
                                    float* __restrict__ h, float* __restrict__ score, int ntot) {
  int lane = threadIdx.x & 63, vl = threadIdx.x >> 6;
  int v = blockIdx.x * 4 + vl;
  if (v >= ntot) return;
  int st = offs[v], c = cnt[v];
  float degv = 1.0f + (float)c;
  float ivd = 1.0f / sqrtf(degv);
  float acc = 0.f;
  for (int j = 0; j < c; ++j) {
    int s = list[st + j];
    float nrm = (1.0f / sqrtf(1.0f + (float)cnt[s])) * ivd;
    acc += h1[(size_t)s * 64 + lane] * nrm;
  }
  float outv = fmaxf(acc + h1[(size_t)v * 64 + lane] * (1.0f / degv) + b[lane], 0.0f);
  h[(size_t)v * 64 + lane] = outv;
  double sc = (double)outv * (double)pvec[lane];
#pragma unroll
  for (int off = 1; off < 64; off <<= 1) sc += __shfl_xor(sc, off);
  if (lane == 0) score[v] = (float)sc * pnbuf[pidx];
}

// ---------------- TopK pool: chunk bitonic + merge-path ----------------

static __global__ void k_chunksort(const float* __restrict__ score,
                                   unsigned long long* __restrict__ runs, int n_per, int k,
                                   int* __restrict__ newidx, int* __restrict__ perm, int single) {
  extern __shared__ unsigned long long sk[];
  int CH = blockDim.x;
  int g0 = blockIdx.x * CH;
  int b = g0 / n_per;
  int i = threadIdx.x;
  int gi = g0 + i;
  int li = gi - b * n_per;
  unsigned u = __float_as_uint(score[gi]);
  unsigned s = (u & 0x80000000u) ? u : ~(u | 0x80000000u);
  sk[i] = ((unsigned long long)s << 32) | (unsigned)li;
  __syncthreads();
  for (int ksz = 2; ksz <= CH; ksz <<= 1) {
    for (int j = ksz >> 1; j > 0; j >>= 1) {
      int ixj = i ^ j;
      if (ixj > i) {
        unsigned long long a = sk[i], c = sk[ixj];
        bool up = ((i & ksz) == 0);
        if ((a > c) == up) {
          sk[i] = c;
          sk[ixj] = a;
        }
      }
      __syncthreads();
    }
  }
  if (!single) {
    runs[gi] = sk[i];
  } else {
    int r = i;
    int idx = (int)(sk[r] & 0xFFFFFFFFu);
    int gidx = b * n_per + idx;
    if (r < k) {
      perm[b * k + r] = gidx;
      newidx[gidx] = b * k + r;
    } else {
      newidx[gidx] = -1;
    }
  }
}

static __global__ void k_merge(const unsigned long long* __restrict__ in,
                               unsigned long long* __restrict__ out, int L, int ntot, int n_per,
                               int k, int* __restrict__ newidx, int* __restrict__ perm,
                               int final) {
  int g = blockIdx.x * 256 + threadIdx.x;
  if (g >= ntot) return;
  unsigned long long key = in[g];
  int pair = g / (2 * L);
  int base = pair * 2 * L;
  int t = g - base;
  const unsigned long long* sib;
  int p;
  if (t < L) {
    sib = in + base + L;
    p = t;
  } else {
    sib = in + base;
    p = t - L;
  }
  int lo = 0, hi = L;
  while (lo < hi) {
    int mid = (lo + hi) >> 1;
    lo = (sib[mid] < key) ? mid + 1 : lo;
    hi = (sib[mid] < key) ? hi : mid;
  }
  int pos = p + lo;
  if (!final) {
    out[base + pos] = key;
  } else {
    int b = base / n_per;
    int idx = (int)(key & 0xFFFFFFFFu);
    int gidx = b * n_per + idx;
    if (pos < k) {
      perm[b * k + pos] = gidx;
      newidx[gidx] = b * k + pos;
    } else {
      newidx[gidx] = -1;
    }
  }
}

static __global__ void k_gather(const float* __restrict__ h, const float* __restrict__ score,
                                const int* __restrict__ perm, float* __restrict__ xnew, int kt) {
  int t = blockIdx.x * 256 + threadIdx.x;
  if (t >= kt * 16) return;
  int nn = t >> 4, q = t & 15;
  int old = perm[nn];
  float tm = tanhf(score[old]);
  float4 v = *(const float4*)&h[(size_t)old * 64 + q * 4];
  v.x *= tm; v.y *= tm; v.z *= tm; v.w *= tm;
  *(float4*)&xnew[(size_t)nn * 64 + q * 4] = v;
}

// ---------------- readout (two-stage parallel) ----------------

static __global__ void k_readout_part(const float* __restrict__ xnew, float* __restrict__ pmax,
                                      float* __restrict__ psum, int k, int nch) {
  int b = blockIdx.x / nch, c = blockIdx.x % nch;
  int d = threadIdx.x & 63, sl = threadIdx.x >> 6;
  int rpc = k / nch;
  const float* p = xnew + ((size_t)b * k + (size_t)c * rpc) * 64 + d;
  float m = -INFINITY, s = 0.0f;
  for (int r = sl; r < rpc; r += 4) {
    float v = p[(size_t)r * 64];
    m = fmaxf(m, v);
    s += v;
  }
  __shared__ float sm[4][64], ss[4][64];
  sm[sl][d] = m;
  ss[sl][d] = s;
  __syncthreads();
  if (sl == 0) {
    m = fmaxf(fmaxf(sm[0][d], sm[1][d]), fmaxf(sm[2][d], sm[3][d]));
    s = ss[0][d] + ss[1][d] + ss[2][d] + ss[3][d];
    pmax[(size_t)blockIdx.x * 64 + d] = m;
    psum[(size_t)blockIdx.x * 64 + d] = s;
  }
}

static __global__ void k_readout_comb(const float* __restrict__ pmax,
                                      const float* __restrict__ psum, float* __restrict__ z,
                                      int k, int nch) {
  int b = blockIdx.x, d = threadIdx.x;
  float m = -INFINITY, s = 0.0f;
  for (int c = 0; c < nch; ++c) {
    m = fmaxf(m, pmax[((size_t)b * nch + c) * 64 + d]);
    s += psum[((size_t)b * nch + c) * 64 + d];
  }
  z[b * 128 + d] += m;
  z[b * 128 + 64 + d] += s / (float)k;
}

// ---------------- MLP + softmax ----------------

static __global__ void k_mlp(const float* __restrict__ z, const float* __restrict__ lw1,
                             const float* __restrict__ lb1, const float* __restrict__ lw2,
                             const float* __restrict__ lb2, const float* __restrict__ lw3,
                             const float* __restrict__ lb3, float* __restrict__ out) {
  __shared__ float zs[128], t1[128], t2[64], t3[256], red[256];
  int b = blockIdx.x, tid = threadIdx.x;
  if (tid < 128) zs[tid] = z[b * 128 + tid];
  __syncthreads();
  if (tid < 128) {
    double a = 0.0;
    for (int d = 0; d < 128; ++d) a += (double)lw1[tid * 128 + d] * (double)zs[d];
    t1[tid] = fmaxf((float)a + lb1[tid], 0.0f);
  }
  __syncthreads();
  if (tid < 64) {
    double a = 0.0;
    for (int d = 0; d < 128; ++d) a += (double)lw2[tid * 128 + d] * (double)t1[d];
    t2[tid] = fmaxf((float)a + lb2[tid], 0.0f);
  }
  __syncthreads();
  {
    double a = 0.0;
    for (int d = 0; d < 64; ++d) a += (double)lw3[tid * 64 + d] * (double)t2[d];
    t3[tid] = (float)a + lb3[tid];
  }
  __syncthreads();
  red[tid] = t3[tid];
  __syncthreads();
  for (int s = 128; s > 0; s >>= 1) {
    if (tid < s) red[tid] = fmaxf(red[tid], red[tid + s]);
    __syncthreads();
  }
  float mx = red[0];
  __syncthreads();
  float e = expf(t3[tid] - mx);
  red[tid] = e;
  __syncthreads();
  for (int s = 128; s > 0; s >>= 1) {
    if (tid < s) red[tid] += red[tid + s];
    __syncthreads();
  }
  out[b * 256 + tid] = e / red[0];
}

// ---------------- launch ----------------

extern "C" void kernel_launch(void* const* d_in, const int* in_sizes, int n_in,
                              void* d_out, int out_size, void* d_ws, size_t ws_size,
                              hipStream_t stream) {
  const float* x0 = (const float*)d_in[0];
  const int* esrc0 = (const int*)d_in[1];
  const int* edst0 = (const int*)d_in[2];
  const float* WL[3] = {(const float*)d_in[3], (const float*)d_in[6], (const float*)d_in[9]};
  const float* BL[3] = {(const float*)d_in[4], (const float*)d_in[7], (const float*)d_in[10]};
  const float* WR[3] = {(const float*)d_in[5], (const float*)d_in[8], (const float*)d_in[11]};
  const float* WG[3] = {(const float*)d_in[12], (const float*)d_in[14], (const float*)d_in[16]};
  const float* BG[3] = {(const float*)d_in[13], (const float*)d_in[15], (const float*)d_in[17]};
  const float* P[6] = {(const float*)d_in[18], (const float*)d_in[19], (const float*)d_in[20],
                       (const float*)d_in[21], (const float*)d_in[22], (const float*)d_in[23]};
  const float* lw1 = (const float*)d_in[24];
  const float* lb1 = (const float*)d_in[25];
  const float* lw2 = (const float*)d_in[26];
  const float* lb2 = (const float*)d_in[27];
  const float* lw3 = (const float*)d_in[28];
  const float* lb3 = (const float*)d_in[29];

  char* ws = (char*)d_ws;
  size_t off = 0;
  auto alloc = [&](size_t bytes) -> void* {
    void* p = ws + off;
    off += (bytes + 255) & ~(size_t)255;
    return p;
  };
  float* hA = (float*)alloc((size_t)65536 * 64 * 4);
  float* hB = (float*)alloc((size_t)32768 * 64 * 4);
  float* mean = (float*)alloc((size_t)32768 * 64 * 4);
  float* tmp = (float*)alloc((size_t)8192 * 64 * 4);
  float* score = (float*)alloc((size_t)65536 * 4);
  int* newidx = (int*)alloc((size_t)65536 * 4);
  int* perm = (int*)alloc((size_t)32768 * 4);
  int* cntA = (int*)alloc((size_t)65536 * 4);
  int* cntB = (int*)alloc((size_t)65536 * 4);
  int* offsA = (int*)alloc((size_t)65536 * 4);
  int* offsB = (int*)alloc((size_t)65536 * 4);
  int* cursor = (int*)alloc((size_t)65536 * 4);
  int* bsum = (int*)alloc((size_t)64 * 4);
  int* listA = (int*)alloc((size_t)NE * 4);
  int* listB = (int*)alloc((size_t)NE * 4);
  float* z = (float*)alloc((size_t)16 * 128 * 4);
  float* pmax = (float*)alloc((size_t)NB * 32 * 64 * 4);
  float* psum = (float*)alloc((size_t)NB * 32 * 64 * 4);
  unsigned long long* keyA = (unsigned long long*)alloc((size_t)65536 * 8);
  unsigned long long* keyB = (unsigned long long*)alloc((size_t)65536 * 8);
  float* pnbuf = (float*)alloc((size_t)64 * 4);
  if (off > ws_size) return;  // workspace too small — bail

  auto scan = [&](int* cntp, int* offsp, int n) {
    int nblk = (n + 1023) / 1024;
    k_scan1<<<nblk, 256, 0, stream>>>(cntp, offsp, bsum, n);
    k_scan2<<<1, 64, 0, stream>>>(bsum, nblk);
    k_scan3<<<(n + 255) / 256, 256, 0, stream>>>(offsp, bsum, n);
  };

  hipMemsetAsync(z, 0, 16 * 128 * 4, stream);
  k_pnorm<<<6, 64, 0, stream>>>(P[0], P[1], P[2], P[3], P[4], P[5], pnbuf);

  // build layer-0 CSR (dst-sorted src lists)
  hipMemsetAsync(cntA, 0, (size_t)65536 * 4, stream);
  k_count<<<NE / 256, 256, 0, stream>>>(edst0, cntA);
  scan(cntA, offsA, 65536);
  hipMemcpyAsync(cursor, offsA, (size_t)65536 * 4, hipMemcpyDeviceToDevice, stream);
  k_fill0<<<NE / 256, 256, 0, stream>>>(esrc0, edst0, cursor, listA);

  const float* xcur = x0;
  int* ccnt = cntA;
  int* coffs = offsA;
  int* clist = listA;

  for (int i = 0; i < 6; ++i) {
    int n_per = N0 >> i;
    int ntot = NB * n_per;
    int k = n_per >> 1;

    if (i == 0) {
      k_sage_gather2<<<(ntot + 255) / 256, 256, 0, stream>>>(xcur, coffs, ccnt, clist, mean, ntot);
      k_sage0<<<(ntot + 15) / 16, 256, 0, stream>>>(xcur, mean, WL[0], BL[0], WR[0], P[0], pnbuf,
                                                    hA, score, ntot);
    } else if (i < 3) {
      k_sage_gather64<<<(ntot + 3) / 4, 256, 0, stream>>>(xcur, coffs, ccnt, clist, mean, ntot);
      k_sage_mm<<<ntot / 64, 256, 0, stream>>>(xcur, mean, WL[i], BL[i], WR[i], P[i], pnbuf, i,
                                               hA, score);
    } else {
      int g = i - 3;
      k_gcn_mm<<<ntot / 64, 256, 0, stream>>>(xcur, WG[g], tmp);
      k_gcn_gather<<<(ntot + 3) / 4, 256, 0, stream>>>(tmp, coffs, ccnt, clist, BG[g], P[i],
                                                       pnbuf, i, hA, score, ntot);
    }

    // pool i: chunk sort + merge-path rounds
    int CH = (n_per < 256) ? n_per : 256;
    int single = (CH == n_per) ? 1 : 0;
    k_chunksort<<<ntot / CH, CH, (size_t)CH * 8, stream>>>(score, keyA, n_per, k, newidx, perm,
                                                           single);
    if (!single) {
      unsigned long long* cur = keyA;
      unsigned long long* nxt = keyB;
      for (int L = CH; L * 2 <= n_per; L <<= 1) {
        int fin = (L * 2 == n_per) ? 1 : 0;
        k_merge<<<(ntot + 255) / 256, 256, 0, stream>>>(cur, nxt, L, ntot, n_per, k, newidx, perm,
                                                        fin);
        unsigned long long* t = cur;
        cur = nxt;
        nxt = t;
      }
    }
    k_gather<<<(NB * k * 16 + 255) / 256, 256, 0, stream>>>(hA, score, perm, hB, NB * k);

    if (i < 5) {
      int newn = NB * k;
      int* ncnt = (i & 1) ? cntA : cntB;
      int* noffs = (i & 1) ? offsA : offsB;
      int* nlist = (i & 1) ? listA : listB;
      k_newcount<<<(newn + 255) / 256, 256, 0, stream>>>(perm, coffs, ccnt, clist, newidx, ncnt,
                                                         newn);
      scan(ncnt, noffs, newn);
      k_newfill<<<(newn + 255) / 256, 256, 0, stream>>>(perm, coffs, ccnt, clist, newidx, noffs,
                                                        nlist, newn);
      ccnt = ncnt;
      coffs = noffs;
      clist = nlist;
    }

    int nch = (k >= 64) ? (k / 64) : 1;
    k_readout_part<<<NB * nch, 256, 0, stream>>>(hB, pmax, psum, k, nch);
    k_readout_comb<<<NB, 64, 0, stream>>>(pmax, psum, z, k, nch);
    xcur = hB;
  }

  k_mlp<<<NB, 256, 0, stream>>>(z, lw1, lb1, lw2, lb2, lw3, lb3, (float*)d_out);
}